// Round 4
// baseline (2786.343 us; speedup 1.0000x reference)
//
#include <hip/hip_runtime.h>
#include <hip/hip_bf16.h>
#include <math.h>

#define A_   12
#define H_   6
#define N_   96
#define T_   80
#define G_   640
#define E_   132
#define E2_  144
#define HC_  1152
#define ROWS_ 7680
#define NCHUNK_ 4
#define GCH_ (G_/NCHUNK_)
#define RCH_ (GCH_*A_)

typedef const __hip_bfloat16* bfp;
typedef __hip_bfloat16 bf16;

__device__ __forceinline__ float b2f(bf16 x){ return __bfloat162float(x); }
__device__ __forceinline__ float ldf(const void* p, size_t i, int f){
    return f ? __bfloat162float(((const bf16*)p)[i]) : ((const float*)p)[i];
}

// dtype probe: even uint16s of f32 storage are random mantissa halves; of bf16
// storage they are genuine bf16 values with sane exponents.
__global__ void k_detect(const void* sf, int* flag)
{
    const unsigned short* u = (const unsigned short*)sf;
    int sane = 0;
    for (int i = 0; i < 64; i++){
        unsigned short v = u[2*i];
        int e = (v >> 7) & 0xFF;
        if (e == 0 || (e >= 100 && e <= 140)) sane++;
    }
    *flag = (sane >= 48) ? 1 : 0;
}

__global__ void k_mlp(const void* sf, const int* ids, const void* emb,
                      const void* W1, const void* b1, const void* g1, const void* be1, const void* m1, const void* v1,
                      const void* W2, const void* b2, const void* g2, const void* be2, const void* m2, const void* v2,
                      const void* W3, const void* b3, const void* g3, const void* be3, const void* m3, const void* v3,
                      const int* flagp, float* xf, void* out0)
{
    __shared__ float in16[16], h1[64], h2[256];
    const int f = *flagp;
    int row = blockIdx.x; int n = row / T_; int t = row % T_;
    int tid = threadIdx.x;
    if (tid < 16) {
        float v;
        if (tid < 4) v = ldf(sf, (size_t)row*4 + tid, f);
        else {
            int id = ids[n]; if (id < 0) id = 0; if (id > 599) id = 599;
            v = ldf(emb, (size_t)id*12 + (tid-4), f);
        }
        in16[tid] = v;
    }
    __syncthreads();
    {
        int o = tid;
        float acc = ldf(b1, o, f);
        #pragma unroll
        for (int i=0;i<16;i++) acc += in16[i]*ldf(W1, i*64+o, f);
        acc = (acc - ldf(m1,o,f)) * rsqrtf(ldf(v1,o,f) + 1e-5f) * ldf(g1,o,f) + ldf(be1,o,f);
        h1[o] = acc > 0.f ? acc : 0.f;
    }
    __syncthreads();
    for (int j=0;j<4;j++){
        int o = tid + 64*j;
        float acc = ldf(b2, o, f);
        for (int i=0;i<64;i++) acc += h1[i]*ldf(W2, i*256+o, f);
        acc = (acc - ldf(m2,o,f)) * rsqrtf(ldf(v2,o,f) + 1e-5f) * ldf(g2,o,f) + ldf(be2,o,f);
        h2[o] = acc > 0.f ? acc : 0.f;
    }
    __syncthreads();
    for (int j=0;j<3;j++){
        int o = tid + 64*j;
        float acc = ldf(b3, o, f);
        for (int i=0;i<256;i++) acc += h2[i]*ldf(W3, i*192+o, f);
        acc = (acc - ldf(m3,o,f)) * rsqrtf(ldf(v3,o,f) + 1e-5f) * ldf(g3,o,f) + ldf(be3,o,f);
        float r = acc > 0.f ? acc : 0.f;
        size_t oi = (size_t)row*192 + o;
        if (f) ((bf16*)out0)[oi] = __float2bfloat16(r);
        else   ((float*)out0)[oi] = r;
        int i2 = o & ~1;
        float div = expf(-logf(10000.f) * (float)i2 / 192.f);
        float ang = (float)t * div;
        float pe = (o & 1) ? cosf(ang) : sinf(ang);
        xf[oi] = r + pe;
    }
}

// gOff: element offset into g/b (per-layer slice)
__global__ void k_ln(const float* __restrict__ x, const void* g, const void* b,
                     size_t gOff, const int* flagp, bf16* out, int permute)
{
    const int f = *flagp;
    int tid = threadIdx.x;
    int row = blockIdx.x*4 + (tid>>6);
    int lane = tid & 63;
    const float* xr = x + (size_t)row*192;
    float v0 = xr[lane], v1 = xr[lane+64], v2 = xr[lane+128];
    float s = v0+v1+v2;
    float q = v0*v0+v1*v1+v2*v2;
    #pragma unroll
    for (int off=32; off; off>>=1){ s += __shfl_xor(s, off); q += __shfl_xor(q, off); }
    float mean = s * (1.f/192.f);
    float var  = q * (1.f/192.f) - mean*mean;
    float rs = rsqrtf(var + 1e-5f);
    int orow = row;
    if (permute){ int n = row/T_, t = row%T_; int bb = n/A_, a = n%A_; orow = (bb*T_+t)*A_ + a; }
    bf16* op = out + (size_t)orow*192;
    op[lane]     = __float2bfloat16((v0-mean)*rs*ldf(g,gOff+lane,f)     + ldf(b,gOff+lane,f));
    op[lane+64]  = __float2bfloat16((v1-mean)*rs*ldf(g,gOff+lane+64,f)  + ldf(b,gOff+lane+64,f));
    op[lane+128] = __float2bfloat16((v2-mean)*rs*ldf(g,gOff+lane+128,f) + ldf(b,gOff+lane+128,f));
}

// A internal bf16; W/bias external with element offsets.
// mode: 0 = store bf16, 1 = exact GELU store bf16, 2 = outf = res + (acc+bias)
__global__ void k_gemm(bfp A, const void* W, size_t wOff, const void* bias, size_t bOff,
                       const int* flagp, bf16* outh, float* outf, const float* __restrict__ res,
                       int K, int N, int mode)
{
    __shared__ float As[16][192];
    const int f = *flagp;
    int tid = threadIdx.x;
    int row0 = blockIdx.x * 16;
    int o = blockIdx.y * 256 + tid;
    float acc[16];
    #pragma unroll
    for (int r=0;r<16;r++) acc[r]=0.f;
    int nchunk = K / 192;
    for (int kc=0;kc<nchunk;kc++){
        for (int idx=tid; idx<16*192; idx+=256){
            int r = idx / 192, k = idx % 192;
            As[r][k] = b2f(A[(size_t)(row0+r)*K + kc*192 + k]);
        }
        __syncthreads();
        if (o < N){
            size_t base = wOff + (size_t)(kc*192)*N + o;
            if (f){
                const bf16* Wp = (const bf16*)W + base;
                for (int k=0;k<192;k+=4){
                    float w0 = b2f(Wp[(size_t)(k+0)*N]);
                    float w1 = b2f(Wp[(size_t)(k+1)*N]);
                    float w2 = b2f(Wp[(size_t)(k+2)*N]);
                    float w3 = b2f(Wp[(size_t)(k+3)*N]);
                    #pragma unroll
                    for (int r=0;r<16;r++)
                        acc[r] += w0*As[r][k] + w1*As[r][k+1] + w2*As[r][k+2] + w3*As[r][k+3];
                }
            } else {
                const float* Wp = (const float*)W + base;
                for (int k=0;k<192;k+=4){
                    float w0 = Wp[(size_t)(k+0)*N];
                    float w1 = Wp[(size_t)(k+1)*N];
                    float w2 = Wp[(size_t)(k+2)*N];
                    float w3 = Wp[(size_t)(k+3)*N];
                    #pragma unroll
                    for (int r=0;r<16;r++)
                        acc[r] += w0*As[r][k] + w1*As[r][k+1] + w2*As[r][k+2] + w3*As[r][k+3];
                }
            }
        }
        __syncthreads();
    }
    if (o < N){
        float bv = ldf(bias, bOff + o, f);
        #pragma unroll 4
        for (int r=0;r<16;r++){
            float v = acc[r] + bv;
            size_t idx = (size_t)(row0+r)*N + o;
            if (mode == 0) outh[idx] = __float2bfloat16(v);
            else if (mode == 1) outh[idx] = __float2bfloat16(0.5f*v*(1.f + erff(v*0.70710678118654752f)));
            else outf[idx] = v + res[idx];
        }
    }
}

__global__ void k_attn(bfp qkv, bf16* attn_o)
{
    __shared__ float Ks[80][32];
    __shared__ float Vs[80][32];
    int bid = blockIdx.x; int n = bid / H_; int h = bid % H_;
    int tid = threadIdx.x;
    for (int idx=tid; idx<80*32; idx+=64){
        int t = idx>>5, c = idx&31;
        const bf16* rp = qkv + (size_t)(n*T_+t)*576;
        Ks[t][c] = b2f(rp[192 + h*32 + c]);
        Vs[t][c] = b2f(rp[384 + h*32 + c]);
    }
    __syncthreads();
    for (int q = tid; q < T_; q += 64){
        float qv[32];
        const bf16* rp = qkv + (size_t)(n*T_+q)*576 + h*32;
        #pragma unroll
        for (int c=0;c<32;c++) qv[c] = b2f(rp[c]);
        float m = -1e30f;
        for (int j=0;j<=q;j++){
            float s=0.f;
            #pragma unroll
            for (int c=0;c<32;c++) s += qv[c]*Ks[j][c];
            s *= 0.17677669529663687f;
            m = fmaxf(m, s);
        }
        float den = 0.f;
        float acc[32];
        #pragma unroll
        for (int c=0;c<32;c++) acc[c]=0.f;
        for (int j=0;j<=q;j++){
            float s=0.f;
            #pragma unroll
            for (int c=0;c<32;c++) s += qv[c]*Ks[j][c];
            s *= 0.17677669529663687f;
            float e = expf(s - m);
            den += e;
            #pragma unroll
            for (int c=0;c<32;c++) acc[c] += e*Vs[j][c];
        }
        float inv = 1.f/den;
        bf16* op = attn_o + (size_t)(n*T_+q)*192 + h*32;
        #pragma unroll
        for (int c=0;c<32;c++) op[c] = __float2bfloat16(acc[c]*inv);
    }
}

__global__ void k_loopea(const int* __restrict__ eidx, const void* ea, const int* flagp, float* lea)
{
    const int f = *flagp;
    int id = blockIdx.x*256 + threadIdx.x;
    if (id >= G_*A_) return;
    int g = id / A_, a = id % A_;
    float s0=0.f, s1=0.f; int cnt=0;
    for (int e=0;e<E_;e++){
        if (eidx[E_ + e] == a){
            s0 += ldf(ea, (size_t)(g*E_+e)*2,   f);
            s1 += ldf(ea, (size_t)(g*E_+e)*2+1, f);
            cnt++;
        }
    }
    if (cnt < 1) cnt = 1;
    lea[id*2]   = s0/(float)cnt;
    lea[id*2+1] = s1/(float)cnt;
}

__global__ void k_alpha(bfp xl, bfp xr,
                        const float* __restrict__ lea, const int* __restrict__ eidx,
                        const void* ea, const void* gwe, size_t geOff,
                        const void* gatt, size_t gaOff, const int* flagp,
                        float* alpha, int g0)
{
    const int f = *flagp;
    int wid = blockIdx.x*4 + (threadIdx.x>>6);
    int lane = threadIdx.x & 63;
    if (wid >= GCH_*E2_) return;
    int gl = wid / E2_, el = wid % E2_;
    int gg = g0 + gl;
    int s, d; float f0, f1;
    if (el < E_){
        s = eidx[el]; d = eidx[E_+el];
        f0 = ldf(ea, (size_t)(gg*E_+el)*2, f); f1 = ldf(ea, (size_t)(gg*E_+el)*2+1, f);
    } else {
        s = d = el - E_;
        f0 = lea[(gg*A_+s)*2]; f1 = lea[(gg*A_+s)*2+1];
    }
    const bf16* xls = xl + (size_t)(gl*A_+s)*HC_;
    const bf16* xrd = xr + (size_t)(gl*A_+d)*HC_;
    for (int h=0; h<H_; h++){
        float p = 0.f;
        #pragma unroll
        for (int c3=0;c3<3;c3++){
            int hc = h*192 + c3*64 + lane;
            float m = b2f(xls[hc]) + b2f(xrd[hc]) + f0*ldf(gwe,geOff+hc,f) + f1*ldf(gwe,geOff+HC_+hc,f);
            m = m > 0.f ? m : 0.2f*m;
            p += m * ldf(gatt,gaOff+hc,f);
        }
        #pragma unroll
        for (int off=32; off; off>>=1) p += __shfl_xor(p, off);
        if (lane==0) alpha[(size_t)wid*H_ + h] = p;
    }
}

__global__ void k_segagg(bfp xl, const float* __restrict__ alpha,
                         const int* __restrict__ eidx, const void* gbias, size_t gbOff,
                         const int* flagp, float* xf, int g0)
{
    __shared__ int e_src[12];
    __shared__ int e_el[12];
    __shared__ float al[12][6];
    __shared__ float w[12][6];
    __shared__ int cnt;
    const int f = *flagp;
    int node = blockIdx.x;
    int gl = node / A_, a = node % A_;
    int gg = g0 + gl;
    int tid = threadIdx.x;
    if (tid==0) cnt = 0;
    __syncthreads();
    if (tid < E_){
        if (eidx[E_+tid] == a){
            int pos = atomicAdd(&cnt, 1);
            if (pos < 12){ e_src[pos] = eidx[tid]; e_el[pos] = tid; }
        }
    } else if (tid == E_){
        int pos = atomicAdd(&cnt, 1);
        if (pos < 12){ e_src[pos] = a; e_el[pos] = E_ + a; }
    }
    __syncthreads();
    if (tid < 72){
        int e = tid / 6, h = tid % 6;
        al[e][h] = alpha[(size_t)(gl*E2_ + e_el[e])*H_ + h];
    }
    __syncthreads();
    if (tid < 6){
        float m = -1e30f;
        for (int e=0;e<12;e++) m = fmaxf(m, al[e][tid]);
        float den = 0.f;
        for (int e=0;e<12;e++){ float ex = expf(al[e][tid]-m); w[e][tid] = ex; den += ex; }
        float inv = 1.f/den;
        for (int e=0;e<12;e++) w[e][tid] *= inv;
    }
    __syncthreads();
    int c = tid;
    float acc = 0.f;
    for (int e=0;e<12;e++){
        const bf16* xp = xl + (size_t)(gl*A_ + e_src[e])*HC_ + c;
        #pragma unroll
        for (int h=0;h<6;h++) acc += w[e][h]*b2f(xp[h*192]);
    }
    int b = gg / T_, t = gg % T_;
    int xrow = (b*A_ + a)*T_ + t;
    xf[(size_t)xrow*192 + c] += acc*(1.f/6.f) + ldf(gbias, gbOff + c, f);
}

__global__ void k_store(const float* __restrict__ xf, void* out, const int* flagp)
{
    const int f = *flagp;
    int i = blockIdx.x*256 + threadIdx.x;
    if (i < ROWS_*192){
        if (f) ((bf16*)out)[1474560 + i] = __float2bfloat16(xf[i]);
        else   ((float*)out)[1474560 + i] = xf[i];
    }
}

extern "C" void kernel_launch(void* const* d_in, const int* in_sizes, int n_in,
                              void* d_out, int out_size, void* d_ws, size_t ws_size,
                              hipStream_t stream)
{
    const void* sf   = d_in[0];
    const int* ids  = (const int*)d_in[2];
    const int* eidx = (const int*)d_in[3];
    const void* ea   = d_in[4];
    const void* emb  = d_in[5];
    const void *laW1=d_in[6],  *lab1=d_in[7];
    const void *bn1g=d_in[8],  *bn1b=d_in[9],  *bn1m=d_in[10], *bn1v=d_in[11];
    const void *laW2=d_in[12], *lab2=d_in[13];
    const void *bn2g=d_in[14], *bn2b=d_in[15], *bn2m=d_in[16], *bn2v=d_in[17];
    const void *laW3=d_in[18], *lab3=d_in[19];
    const void *bn3g=d_in[20], *bn3b=d_in[21], *bn3m=d_in[22], *bn3v=d_in[23];
    const void *ln1g=d_in[24], *ln1b=d_in[25];
    const void *qkvw=d_in[26], *qkvb=d_in[27];
    const void *outw=d_in[28], *outb=d_in[29];
    const void *ln2g=d_in[30], *ln2b=d_in[31];
    const void *fw1 =d_in[32], *fb1 =d_in[33];
    const void *fw2 =d_in[34], *fb2 =d_in[35];
    const void *gwl =d_in[36], *gbl =d_in[37];
    const void *gwr =d_in[38], *gbr =d_in[39];
    const void *gwe =d_in[40];
    const void *gatt=d_in[41];
    const void *gbias=d_in[42];
    const void *ng  =d_in[43], *nb  =d_in[44];

    float* ws = (float*)d_ws;
    float* xf  = ws;
    bf16*  xn  = (bf16*)(ws + 1474560);
    bf16*  qkv = (bf16*)(ws + 2211840);
    bf16*  ao  = (bf16*)(ws + 4423680);
    bf16*  hb  = (bf16*)(ws + 2211840);
    bf16*  xlc = (bf16*)(ws + 2211840);
    bf16*  xrc = (bf16*)(ws + 3317760);
    float* lea = ws + 5160960;
    float* alp = ws + 5176320;
    int*  flag = (int*)(ws + 5314560);
    (void)ws_size; (void)in_sizes; (void)n_in; (void)out_size;

    k_detect<<<1, 1, 0, stream>>>(sf, flag);
    k_mlp<<<ROWS_, 64, 0, stream>>>(sf, ids, emb,
        laW1, lab1, bn1g, bn1b, bn1m, bn1v,
        laW2, lab2, bn2g, bn2b, bn2m, bn2v,
        laW3, lab3, bn3g, bn3b, bn3m, bn3v, flag, xf, d_out);
    k_loopea<<<(G_*A_+255)/256, 256, 0, stream>>>(eidx, ea, flag, lea);

    for (int l=0; l<3; l++){
        k_ln<<<ROWS_/4, 256, 0, stream>>>(xf, ln1g, ln1b, (size_t)l*192, flag, xn, 0);
        k_gemm<<<dim3(ROWS_/16, 3), 256, 0, stream>>>(xn, qkvw, (size_t)l*192*576, qkvb, (size_t)l*576,
                                                      flag, qkv, nullptr, nullptr, 192, 576, 0);
        k_attn<<<N_*H_, 64, 0, stream>>>(qkv, ao);
        k_gemm<<<dim3(ROWS_/16, 1), 256, 0, stream>>>(ao, outw, (size_t)l*192*192, outb, (size_t)l*192,
                                                      flag, nullptr, xf, xf, 192, 192, 2);
        k_ln<<<ROWS_/4, 256, 0, stream>>>(xf, ln2g, ln2b, (size_t)l*192, flag, xn, 0);
        k_gemm<<<dim3(ROWS_/16, 3), 256, 0, stream>>>(xn, fw1, (size_t)l*192*768, fb1, (size_t)l*768,
                                                      flag, hb, nullptr, nullptr, 192, 768, 1);
        k_gemm<<<dim3(ROWS_/16, 1), 256, 0, stream>>>(hb, fw2, (size_t)l*768*192, fb2, (size_t)l*192,
                                                      flag, nullptr, xf, xf, 768, 192, 2);
        k_ln<<<ROWS_/4, 256, 0, stream>>>(xf, ng, nb, (size_t)l*192, flag, xn, 1);
        for (int c=0; c<NCHUNK_; c++){
            int g0 = c*GCH_;
            const bf16* xnc = xn + (size_t)g0*A_*192;
            k_gemm<<<dim3(RCH_/16, 5), 256, 0, stream>>>(xnc, gwl, (size_t)l*192*1152, gbl, (size_t)l*1152,
                                                         flag, xlc, nullptr, nullptr, 192, 1152, 0);
            k_gemm<<<dim3(RCH_/16, 5), 256, 0, stream>>>(xnc, gwr, (size_t)l*192*1152, gbr, (size_t)l*1152,
                                                         flag, xrc, nullptr, nullptr, 192, 1152, 0);
            k_alpha<<<GCH_*E2_/4, 256, 0, stream>>>(xlc, xrc, lea, eidx, ea,
                                                    gwe, (size_t)l*2*1152, gatt, (size_t)l*1152,
                                                    flag, alp, g0);
            k_segagg<<<GCH_*A_, 192, 0, stream>>>(xlc, alp, eidx, gbias, (size_t)l*192, flag, xf, g0);
        }
    }
    k_store<<<(ROWS_*192+255)/256, 256, 0, stream>>>(xf, d_out, flag);
}

// Round 5
// 2740.086 us; speedup vs baseline: 1.0169x; 1.0169x over previous
//
#include <hip/hip_runtime.h>
#include <hip/hip_bf16.h>
#include <math.h>

#define A_   12
#define H_   6
#define N_   96
#define T_   80
#define G_   640
#define E_   132
#define E2_  144
#define ROWS_ 7680
#define NCHUNK_ 4
#define GCH_ (G_/NCHUNK_)        /* 160 graphs per chunk */
#define RCH_ (GCH_*A_)           /* 1920 rows per chunk */

typedef const __hip_bfloat16* bfp;
typedef __hip_bfloat16 bf16;
typedef __attribute__((ext_vector_type(8))) short short8;
typedef __attribute__((ext_vector_type(4))) float f32x4;

// ---- bf16 weight arena element offsets (in bf16 units) ----
#define WB_QKV   0                /* [3][576][192]  */
#define WB_OUT   331776           /* [3][192][192]  */
#define WB_FW1   442368           /* [3][768][192]  */
#define WB_FW2   884736           /* [3][192][768]  */
#define WB_GAT   1327104          /* [3][2304][192] (gwl|gwr) */
#define WB_W1    2654208          /* [16][64] BN-folded */
#define WB_W2    2655232          /* [64][256] BN-folded */
#define WB_W3T   2671616          /* [192][256] BN-folded, transposed */
#define WB_TOT   2720768
// ---- f32 bias arena element offsets ----
#define BB_QKV   0                /* [3][576] */
#define BB_OUT   1728             /* [3][192] */
#define BB_FW1   2304             /* [3][768] */
#define BB_FW2   4608             /* [3][192] */
#define BB_GAT   5184             /* [3][2304] */
#define BB_B1    12096            /* [64]  folded */
#define BB_B2    12160            /* [256] folded */
#define BB_B3    12416            /* [192] folded */
#define BB_TOT   12608

__device__ __forceinline__ float b2f(bf16 x){ return __bfloat162float(x); }
__device__ __forceinline__ float ldf(const void* p, size_t i, int f){
    return f ? __bfloat162float(((const bf16*)p)[i]) : ((const float*)p)[i];
}

// dtype probe: even uint16s of f32 storage are random mantissa halves.
__global__ void k_detect(const void* sf, int* flag)
{
    const unsigned short* u = (const unsigned short*)sf;
    int sane = 0;
    for (int i = 0; i < 64; i++){
        unsigned short v = u[2*i];
        int e = (v >> 7) & 0xFF;
        if (e == 0 || (e >= 100 && e <= 140)) sane++;
    }
    *flag = (sane >= 48) ? 1 : 0;
}

// ---- convert+transpose all weights into bf16 arena; biases (BN-folded) into f32 arena ----
__global__ __launch_bounds__(256) void k_convert(
    const void* qkvw, const void* outw, const void* fw1, const void* fw2,
    const void* gwl, const void* gwr,
    const void* W1, const void* b1, const void* g1, const void* be1, const void* m1, const void* v1,
    const void* W2, const void* b2, const void* g2, const void* be2, const void* m2, const void* v2,
    const void* W3, const void* b3, const void* g3, const void* be3, const void* m3, const void* v3,
    const void* qkvb, const void* outb, const void* fb1, const void* fb2,
    const void* gbl, const void* gbr,
    const int* flagp, bf16* WB, float* BB)
{
    const int f = *flagp;
    size_t idx = (size_t)blockIdx.x*256 + threadIdx.x;
    if (idx < WB_TOT){
        float v;
        if (idx < WB_OUT){            size_t i=idx-WB_QKV; int l=i/110592; int r=i%110592; int n=r/192, k=r%192;
            v = ldf(qkvw, (size_t)l*110592 + (size_t)k*576 + n, f);
        } else if (idx < WB_FW1){     size_t i=idx-WB_OUT; int l=i/36864; int r=i%36864; int n=r/192, k=r%192;
            v = ldf(outw, (size_t)l*36864 + (size_t)k*192 + n, f);
        } else if (idx < WB_FW2){     size_t i=idx-WB_FW1; int l=i/147456; int r=i%147456; int n=r/192, k=r%192;
            v = ldf(fw1, (size_t)l*147456 + (size_t)k*768 + n, f);
        } else if (idx < WB_GAT){     size_t i=idx-WB_FW2; int l=i/147456; int r=i%147456; int n=r/768, k=r%768;
            v = ldf(fw2, (size_t)l*147456 + (size_t)k*192 + n, f);
        } else if (idx < WB_W1){      size_t i=idx-WB_GAT; int l=i/442368; int r=i%442368; int n=r/192, k=r%192;
            if (n < 1152) v = ldf(gwl, (size_t)l*221184 + (size_t)k*1152 + n, f);
            else          v = ldf(gwr, (size_t)l*221184 + (size_t)k*1152 + (n-1152), f);
        } else if (idx < WB_W2){      size_t i=idx-WB_W1; int o=i%64;
            float s = ldf(g1,o,f)*rsqrtf(ldf(v1,o,f)+1e-5f);
            v = ldf(W1, i, f) * s;
        } else if (idx < WB_W3T){     size_t i=idx-WB_W2; int o=i%256;
            float s = ldf(g2,o,f)*rsqrtf(ldf(v2,o,f)+1e-5f);
            v = ldf(W2, i, f) * s;
        } else {                      size_t i=idx-WB_W3T; int n=i/256, k=i%256;
            float s = ldf(g3,n,f)*rsqrtf(ldf(v3,n,f)+1e-5f);
            v = ldf(W3, (size_t)k*192 + n, f) * s;
        }
        WB[idx] = __float2bfloat16(v);
    } else if (idx < WB_TOT + BB_TOT){
        size_t j = idx - WB_TOT;
        float v;
        if (j < BB_OUT)        v = ldf(qkvb, j, f);
        else if (j < BB_FW1)   v = ldf(outb, j-BB_OUT, f);
        else if (j < BB_FW2)   v = ldf(fb1, j-BB_FW1, f);
        else if (j < BB_GAT)   v = ldf(fb2, j-BB_FW2, f);
        else if (j < BB_B1){   size_t i=j-BB_GAT; int l=i/2304; int o=i%2304;
            v = (o<1152) ? ldf(gbl, (size_t)l*1152+o, f) : ldf(gbr, (size_t)l*1152+o-1152, f);
        } else if (j < BB_B2){ int o=j-BB_B1;
            float s = ldf(g1,o,f)*rsqrtf(ldf(v1,o,f)+1e-5f);
            v = (ldf(b1,o,f)-ldf(m1,o,f))*s + ldf(be1,o,f);
        } else if (j < BB_B3){ int o=j-BB_B2;
            float s = ldf(g2,o,f)*rsqrtf(ldf(v2,o,f)+1e-5f);
            v = (ldf(b2,o,f)-ldf(m2,o,f))*s + ldf(be2,o,f);
        } else {               int o=j-BB_B3;
            float s = ldf(g3,o,f)*rsqrtf(ldf(v3,o,f)+1e-5f);
            v = (ldf(b3,o,f)-ldf(m3,o,f))*s + ldf(be3,o,f);
        }
        BB[j] = v;
    }
}

// ---- MLP stages 1+2: in16 -> 64 -> 256 (relu, BN folded), 16 rows/block ----
__global__ __launch_bounds__(256) void k_mlp_a(
    const void* sf, const int* ids, const void* emb, const int* flagp,
    const bf16* __restrict__ WB, const float* __restrict__ BB, bf16* h2g)
{
    __shared__ float in16[16][16];
    __shared__ float h1[16][64];
    const int f = *flagp;
    int tid = threadIdx.x;
    int row0 = blockIdx.x * 16;
    {
        int r = tid >> 4, i = tid & 15;
        int row = row0 + r;
        float v;
        if (i < 4) v = ldf(sf, (size_t)row*4 + i, f);
        else {
            int id = ids[row / T_]; if (id < 0) id = 0; if (id > 599) id = 599;
            v = ldf(emb, (size_t)id*12 + (i-4), f);
        }
        in16[r][i] = v;
    }
    __syncthreads();
    {
        int o = tid & 63, rg = tid >> 6;
        float acc[4];
        float bv = BB[BB_B1 + o];
        #pragma unroll
        for (int j=0;j<4;j++) acc[j] = bv;
        for (int i=0;i<16;i++){
            float w = b2f(WB[WB_W1 + i*64 + o]);
            #pragma unroll
            for (int j=0;j<4;j++) acc[j] += in16[rg*4+j][i]*w;
        }
        #pragma unroll
        for (int j=0;j<4;j++) h1[rg*4+j][o] = acc[j] > 0.f ? acc[j] : 0.f;
    }
    __syncthreads();
    {
        int o = tid;
        float acc[16];
        float bv = BB[BB_B2 + o];
        #pragma unroll
        for (int r=0;r<16;r++) acc[r] = bv;
        for (int i=0;i<64;i++){
            float w = b2f(WB[WB_W2 + i*256 + o]);
            #pragma unroll
            for (int r=0;r<16;r++) acc[r] += h1[r][i]*w;
        }
        for (int r=0;r<16;r++){
            float v = acc[r] > 0.f ? acc[r] : 0.f;
            h2g[(size_t)(row0+r)*256 + o] = __float2bfloat16(v);
        }
    }
}

// ---- MFMA GEMM: C[rows x N] = A[rows x K](bf16) @ Wt[N x K]^T + bias ----
// block tile 64x64; 4 waves, each 16 rows x 64 cols; K in 192-chunks.
// mode 0: bf16 store | 1: GELU bf16 | 2: outf = res + v | 3: relu -> out0(flag dtype) & xf = relu + PE
__global__ __launch_bounds__(256) void k_mgemm(
    const bf16* __restrict__ A, const bf16* __restrict__ Wt, const float* __restrict__ bias,
    bf16* outh, float* outf, const float* __restrict__ res, void* out0, const int* flagp,
    int K, int N, int mode)
{
    __shared__ short As[64*200];
    __shared__ short Bs[64*200];
    int tid = threadIdx.x;
    int w = tid >> 6, lane = tid & 63, q = lane >> 4, li = lane & 15;
    int m0 = blockIdx.x * 64, n0 = blockIdx.y * 64;
    const int f = flagp ? *flagp : 0;
    f32x4 acc[4];
    #pragma unroll
    for (int nt=0;nt<4;nt++) acc[nt] = (f32x4){0.f,0.f,0.f,0.f};
    int nkc = (K + 191) / 192;
    for (int kc = 0; kc < nkc; kc++){
        int kcw = K - kc*192; if (kcw > 192) kcw = 192;
        int vr = kcw >> 3;
        const bf16* Ab = A  + (size_t)m0*K + kc*192;
        const bf16* Bb = Wt + (size_t)n0*K + kc*192;
        for (int idx = tid; idx < 64*vr; idx += 256){
            int r = idx / vr, kv = idx - r*vr;
            *(short8*)&As[r*200 + kv*8] = *(const short8*)&Ab[(size_t)r*K + kv*8];
        }
        for (int idx = tid; idx < 64*vr; idx += 256){
            int r = idx / vr, kv = idx - r*vr;
            *(short8*)&Bs[r*200 + kv*8] = *(const short8*)&Bb[(size_t)r*K + kv*8];
        }
        __syncthreads();
        int kkn = kcw >> 5;
        for (int kk = 0; kk < kkn; kk++){
            int ko = kk*32 + q*8;
            short8 a = *(short8*)&As[(w*16+li)*200 + ko];
            #pragma unroll
            for (int nt = 0; nt < 4; nt++){
                short8 b = *(short8*)&Bs[(nt*16+li)*200 + ko];
                acc[nt] = __builtin_amdgcn_mfma_f32_16x16x32_bf16(a, b, acc[nt], 0, 0, 0);
            }
        }
        __syncthreads();
    }
    int rb = m0 + w*16 + q*4;
    #pragma unroll
    for (int nt = 0; nt < 4; nt++){
        int col = n0 + nt*16 + li;
        float bv = bias[col];
        #pragma unroll
        for (int p = 0; p < 4; p++){
            int row = rb + p;
            float v = acc[nt][p] + bv;
            size_t idx = (size_t)row*N + col;
            if (mode == 0) outh[idx] = __float2bfloat16(v);
            else if (mode == 1) outh[idx] = __float2bfloat16(0.5f*v*(1.f + erff(v*0.70710678118654752f)));
            else if (mode == 2) outf[idx] = v + res[idx];
            else {
                float r2 = v > 0.f ? v : 0.f;
                if (f) ((bf16*)out0)[idx] = __float2bfloat16(r2);
                else   ((float*)out0)[idx] = r2;
                int t = row % T_;
                int i2 = col & ~1;
                float dv = expf((float)i2 * (-9.210340371976184f/192.f));
                float ang = (float)t * dv;
                outf[idx] = r2 + ((col & 1) ? cosf(ang) : sinf(ang));
            }
        }
    }
}

// ---- LayerNorm (one wave per row), optional permute to node order ----
__global__ __launch_bounds__(256) void k_ln(const float* __restrict__ x, const void* g, const void* b,
                     size_t gOff, const int* flagp, bf16* out, int permute)
{
    const int f = *flagp;
    int tid = threadIdx.x;
    int row = blockIdx.x*4 + (tid>>6);
    int lane = tid & 63;
    const float* xr = x + (size_t)row*192;
    float v0 = xr[lane], v1 = xr[lane+64], v2 = xr[lane+128];
    float s = v0+v1+v2;
    float qq = v0*v0+v1*v1+v2*v2;
    #pragma unroll
    for (int off=32; off; off>>=1){ s += __shfl_xor(s, off); qq += __shfl_xor(qq, off); }
    float mean = s * (1.f/192.f);
    float var  = qq * (1.f/192.f) - mean*mean;
    float rs = rsqrtf(var + 1e-5f);
    int orow = row;
    if (permute){ int n = row/T_, t = row%T_; int bb = n/A_, a = n%A_; orow = (bb*T_+t)*A_ + a; }
    bf16* op = out + (size_t)orow*192;
    op[lane]     = __float2bfloat16((v0-mean)*rs*ldf(g,gOff+lane,f)     + ldf(b,gOff+lane,f));
    op[lane+64]  = __float2bfloat16((v1-mean)*rs*ldf(g,gOff+lane+64,f)  + ldf(b,gOff+lane+64,f));
    op[lane+128] = __float2bfloat16((v2-mean)*rs*ldf(g,gOff+lane+128,f) + ldf(b,gOff+lane+128,f));
}

// ---- causal attention, one wave per (sequence, head) ----
__global__ __launch_bounds__(64) void k_attn(bfp qkv, bf16* attn_o)
{
    __shared__ float Ks[80][32];
    __shared__ float Vs[80][32];
    int bid = blockIdx.x; int n = bid / H_; int h = bid % H_;
    int tid = threadIdx.x;
    for (int idx=tid; idx<80*32; idx+=64){
        int t = idx>>5, c = idx&31;
        const bf16* rp = qkv + (size_t)(n*T_+t)*576;
        Ks[t][c] = b2f(rp[192 + h*32 + c]);
        Vs[t][c] = b2f(rp[384 + h*32 + c]);
    }
    __syncthreads();
    for (int q = tid; q < T_; q += 64){
        float qv[32];
        const bf16* rp = qkv + (size_t)(n*T_+q)*576 + h*32;
        #pragma unroll
        for (int c=0;c<32;c++) qv[c] = b2f(rp[c]);
        float m = -1e30f;
        for (int j=0;j<=q;j++){
            float sv=0.f;
            #pragma unroll
            for (int c=0;c<32;c++) sv += qv[c]*Ks[j][c];
            m = fmaxf(m, sv*0.17677669529663687f);
        }
        float den = 0.f;
        float acc[32];
        #pragma unroll
        for (int c=0;c<32;c++) acc[c]=0.f;
        for (int j=0;j<=q;j++){
            float sv=0.f;
            #pragma unroll
            for (int c=0;c<32;c++) sv += qv[c]*Ks[j][c];
            float e = expf(sv*0.17677669529663687f - m);
            den += e;
            #pragma unroll
            for (int c=0;c<32;c++) acc[c] += e*Vs[j][c];
        }
        float inv = 1.f/den;
        bf16* op = attn_o + (size_t)(n*T_+q)*192 + h*32;
        #pragma unroll
        for (int c=0;c<32;c++) op[c] = __float2bfloat16(acc[c]*inv);
    }
}

// ---- self-loop attr = mean of incoming edge attrs ----
__global__ __launch_bounds__(256) void k_loopea(const int* __restrict__ eidx, const void* ea, const int* flagp, float* lea)
{
    const int f = *flagp;
    int id = blockIdx.x*256 + threadIdx.x;
    if (id >= G_*A_) return;
    int g = id / A_, a = id % A_;
    float s0=0.f, s1=0.f; int cnt=0;
    for (int e=0;e<E_;e++){
        if (eidx[E_ + e] == a){
            s0 += ldf(ea, (size_t)(g*E_+e)*2,   f);
            s1 += ldf(ea, (size_t)(g*E_+e)*2+1, f);
            cnt++;
        }
    }
    if (cnt < 1) cnt = 1;
    lea[id*2]   = s0/(float)cnt;
    lea[id*2+1] = s1/(float)cnt;
}

// ---- fused GATv2: edge logits + segment softmax + aggregate; one block per graph ----
__global__ __launch_bounds__(256) void k_gat(
    bfp xlr, const float* __restrict__ lea, const int* __restrict__ eidx,
    const void* ea, const void* gwe, size_t geOff, const void* gatt, size_t gaOff,
    const void* gbias, size_t gbOff, const int* flagp, float* xf, int g0)
{
    __shared__ int es[E2_], ed[E2_];
    __shared__ float sAl[E2_][H_];
    __shared__ int nl[A_][A_];
    __shared__ int ncnt[A_];
    const int f = *flagp;
    int gl = blockIdx.x;
    int gg = g0 + gl;
    int tid = threadIdx.x;
    int w = tid >> 6, lane = tid & 63;
    if (tid < A_) ncnt[tid] = 0;
    if (tid < E_){ es[tid] = eidx[tid]; ed[tid] = eidx[E_+tid]; }
    else if (tid < E2_){ es[tid] = tid - E_; ed[tid] = tid - E_; }
    __syncthreads();
    if (tid < E2_){
        int d = ed[tid];
        int pos = atomicAdd(&ncnt[d], 1);
        nl[d][pos] = tid;
    }
    __syncthreads();
    // phase 1: edge logits
    for (int e = w; e < E2_; e += 4){
        int s = es[e], d = ed[e];
        float f0, f1;
        if (e < E_){
            f0 = ldf(ea, (size_t)(gg*E_+e)*2,   f);
            f1 = ldf(ea, (size_t)(gg*E_+e)*2+1, f);
        } else {
            f0 = lea[(gg*A_+s)*2]; f1 = lea[(gg*A_+s)*2+1];
        }
        const bf16* xls = xlr + (size_t)(gl*A_+s)*2304;
        const bf16* xrd = xlr + (size_t)(gl*A_+d)*2304 + 1152;
        for (int h=0; h<H_; h++){
            float p = 0.f;
            #pragma unroll
            for (int c3=0;c3<3;c3++){
                int hc = h*192 + c3*64 + lane;
                float m = b2f(xls[hc]) + b2f(xrd[hc]) + f0*ldf(gwe,geOff+hc,f) + f1*ldf(gwe,geOff+1152+hc,f);
                m = m > 0.f ? m : 0.2f*m;
                p += m * ldf(gatt,gaOff+hc,f);
            }
            #pragma unroll
            for (int off=32; off; off>>=1) p += __shfl_xor(p, off);
            if (lane==0) sAl[e][h] = p;
        }
    }
    __syncthreads();
    // phase 2: segment softmax per (node, head)
    if (tid < A_*H_){
        int a = tid / H_, h = tid % H_;
        float m = -1e30f;
        #pragma unroll
        for (int j=0;j<A_;j++) m = fmaxf(m, sAl[nl[a][j]][h]);
        float den = 0.f;
        float ex[A_];
        #pragma unroll
        for (int j=0;j<A_;j++){ ex[j] = expf(sAl[nl[a][j]][h]-m); den += ex[j]; }
        float inv = 1.f/den;
        #pragma unroll
        for (int j=0;j<A_;j++) sAl[nl[a][j]][h] = ex[j]*inv;
    }
    __syncthreads();
    // phase 3: aggregate
    int bb = gg / T_, t = gg % T_;
    for (int oi = tid; oi < A_*192; oi += 256){
        int a = oi / 192, c = oi % 192;
        float acc = 0.f;
        #pragma unroll
        for (int j=0;j<A_;j++){
            int e = nl[a][j];
            const bf16* xp = xlr + (size_t)(gl*A_ + es[e])*2304 + c;
            #pragma unroll
            for (int h=0;h<H_;h++) acc += sAl[e][h]*b2f(xp[h*192]);
        }
        int xrow = (bb*A_ + a)*T_ + t;
        xf[(size_t)xrow*192 + c] += acc*(1.f/6.f) + ldf(gbias, gbOff + c, f);
    }
}

__global__ __launch_bounds__(256) void k_store(const float* __restrict__ xf, void* out, const int* flagp)
{
    const int f = *flagp;
    int i = blockIdx.x*256 + threadIdx.x;
    if (i < ROWS_*192){
        if (f) ((bf16*)out)[1474560 + i] = __float2bfloat16(xf[i]);
        else   ((float*)out)[1474560 + i] = xf[i];
    }
}

extern "C" void kernel_launch(void* const* d_in, const int* in_sizes, int n_in,
                              void* d_out, int out_size, void* d_ws, size_t ws_size,
                              hipStream_t stream)
{
    const void* sf   = d_in[0];
    const int* ids  = (const int*)d_in[2];
    const int* eidx = (const int*)d_in[3];
    const void* ea   = d_in[4];
    const void* emb  = d_in[5];
    const void *laW1=d_in[6],  *lab1=d_in[7];
    const void *bn1g=d_in[8],  *bn1b=d_in[9],  *bn1m=d_in[10], *bn1v=d_in[11];
    const void *laW2=d_in[12], *lab2=d_in[13];
    const void *bn2g=d_in[14], *bn2b=d_in[15], *bn2m=d_in[16], *bn2v=d_in[17];
    const void *laW3=d_in[18], *lab3=d_in[19];
    const void *bn3g=d_in[20], *bn3b=d_in[21], *bn3m=d_in[22], *bn3v=d_in[23];
    const void *ln1g=d_in[24], *ln1b=d_in[25];
    const void *qkvw=d_in[26], *qkvb=d_in[27];
    const void *outw=d_in[28], *outb=d_in[29];
    const void *ln2g=d_in[30], *ln2b=d_in[31];
    const void *fw1 =d_in[32], *fb1 =d_in[33];
    const void *fw2 =d_in[34], *fb2 =d_in[35];
    const void *gwl =d_in[36], *gbl =d_in[37];
    const void *gwr =d_in[38], *gbr =d_in[39];
    const void *gwe =d_in[40];
    const void *gatt=d_in[41];
    const void *gbias=d_in[42];
    const void *ng  =d_in[43], *nb  =d_in[44];

    float* ws = (float*)d_ws;
    // layout (f32 units)
    float* xf  = ws;                          // [0, 1474560)
    bf16*  xn  = (bf16*)(ws + 1474560);       // 1,474,560 bf16
    bf16*  qkv = (bf16*)(ws + 2211840);       // 4,423,680 bf16  [2211840, 4423680)
    bf16*  ao  = (bf16*)(ws + 4423680);       // 1,474,560 bf16  [4423680, 5160960)
    bf16*  hb  = (bf16*)(ws + 2211840);       // overlays qkv+ao (FFN hidden)
    bf16*  h2  = (bf16*)(ws + 2211840);       // overlays (MLP hidden, 1,966,080 bf16)
    bf16*  xlr = (bf16*)(ws + 2211840);       // overlays (GAT chunk lr, 4,423,680 bf16)
    float* lea = ws + 5160960;                // 15,360
    int*  flag = (int*)(ws + 5176320);
    bf16*  WB  = (bf16*)(ws + 5176328);       // 2,720,768 bf16 -> 1,360,384 f32
    float* BB  = ws + 6536712;                // 12,608 f32
    (void)ws_size; (void)in_sizes; (void)n_in; (void)out_size;

    k_detect<<<1, 1, 0, stream>>>(sf, flag);
    k_convert<<<(WB_TOT+BB_TOT+255)/256, 256, 0, stream>>>(
        qkvw, outw, fw1, fw2, gwl, gwr,
        laW1, lab1, bn1g, bn1b, bn1m, bn1v,
        laW2, lab2, bn2g, bn2b, bn2m, bn2v,
        laW3, lab3, bn3g, bn3b, bn3m, bn3v,
        qkvb, outb, fb1, fb2, gbl, gbr, flag, WB, BB);
    k_mlp_a<<<ROWS_/16, 256, 0, stream>>>(sf, ids, emb, flag, WB, BB, h2);
    // MLP stage 3: h2 @ W3 (K=256, N=192), relu + PE -> out0 + xf
    k_mgemm<<<dim3(ROWS_/64, 3), 256, 0, stream>>>(h2, WB + WB_W3T, BB + BB_B3,
        nullptr, xf, nullptr, d_out, flag, 256, 192, 3);
    k_loopea<<<(G_*A_+255)/256, 256, 0, stream>>>(eidx, ea, flag, lea);

    for (int l=0; l<3; l++){
        k_ln<<<ROWS_/4, 256, 0, stream>>>(xf, ln1g, ln1b, (size_t)l*192, flag, xn, 0);
        k_mgemm<<<dim3(ROWS_/64, 9), 256, 0, stream>>>(xn, WB + WB_QKV + (size_t)l*110592,
            BB + BB_QKV + l*576, qkv, nullptr, nullptr, nullptr, nullptr, 192, 576, 0);
        k_attn<<<N_*H_, 64, 0, stream>>>(qkv, ao);
        k_mgemm<<<dim3(ROWS_/64, 3), 256, 0, stream>>>(ao, WB + WB_OUT + (size_t)l*36864,
            BB + BB_OUT + l*192, nullptr, xf, xf, nullptr, nullptr, 192, 192, 2);
        k_ln<<<ROWS_/4, 256, 0, stream>>>(xf, ln2g, ln2b, (size_t)l*192, flag, xn, 0);
        k_mgemm<<<dim3(ROWS_/64, 12), 256, 0, stream>>>(xn, WB + WB_FW1 + (size_t)l*147456,
            BB + BB_FW1 + l*768, hb, nullptr, nullptr, nullptr, nullptr, 192, 768, 1);
        k_mgemm<<<dim3(ROWS_/64, 3), 256, 0, stream>>>(hb, WB + WB_FW2 + (size_t)l*147456,
            BB + BB_FW2 + l*192, nullptr, xf, xf, nullptr, nullptr, 768, 192, 2);
        k_ln<<<ROWS_/4, 256, 0, stream>>>(xf, ng, nb, (size_t)l*192, flag, xn, 1);
        for (int c=0; c<NCHUNK_; c++){
            int g0 = c*GCH_;
            const bf16* xnc = xn + (size_t)g0*A_*192;
            k_mgemm<<<dim3(RCH_/64, 36), 256, 0, stream>>>(xnc, WB + WB_GAT + (size_t)l*442368,
                BB + BB_GAT + l*2304, xlr, nullptr, nullptr, nullptr, nullptr, 192, 2304, 0);
            k_gat<<<GCH_, 256, 0, stream>>>(xlr, lea, eidx, ea,
                gwe, (size_t)l*2*1152, gatt, (size_t)l*1152,
                gbias, (size_t)l*192, flag, xf, g0);
        }
    }
    k_store<<<(ROWS_*192+255)/256, 256, 0, stream>>>(xf, d_out, flag);
}

// Round 6
// 1356.365 us; speedup vs baseline: 2.0543x; 2.0202x over previous
//
#include <hip/hip_runtime.h>
#include <hip/hip_bf16.h>
#include <math.h>

#define A_   12
#define H_   6
#define N_   96
#define T_   80
#define G_   640
#define E_   132
#define E2_  144
#define ROWS_ 7680
#define NCHUNK_ 4
#define GCH_ (G_/NCHUNK_)        /* 160 graphs per chunk */
#define RCH_ (GCH_*A_)           /* 1920 rows per chunk */

typedef const __hip_bfloat16* bfp;
typedef __hip_bfloat16 bf16;
typedef __attribute__((ext_vector_type(8))) short short8;
typedef __attribute__((ext_vector_type(4))) float f32x4;

// ---- bf16 weight arena element offsets (in bf16 units) ----
#define WB_QKV   0                /* [3][576][192]  */
#define WB_OUT   331776           /* [3][192][192]  */
#define WB_FW1   442368           /* [3][768][192]  */
#define WB_FW2   884736           /* [3][192][768]  */
#define WB_GAT   1327104          /* [3][2304][192] (gwl|gwr) */
#define WB_W1    2654208          /* [16][64] BN-folded */
#define WB_W2    2655232          /* [64][256] BN-folded */
#define WB_W3T   2671616          /* [192][256] BN-folded, transposed */
#define WB_TOT   2720768
// ---- f32 bias arena element offsets ----
#define BB_QKV   0                /* [3][576] */
#define BB_OUT   1728             /* [3][192] */
#define BB_FW1   2304             /* [3][768] */
#define BB_FW2   4608             /* [3][192] */
#define BB_GAT   5184             /* [3][2304] */
#define BB_B1    12096            /* [64]  folded */
#define BB_B2    12160            /* [256] folded */
#define BB_B3    12416            /* [192] folded */
#define BB_TOT   12608

__device__ __forceinline__ float b2f(bf16 x){ return __bfloat162float(x); }
__device__ __forceinline__ float ldf(const void* p, size_t i, int f){
    return f ? __bfloat162float(((const bf16*)p)[i]) : ((const float*)p)[i];
}

// dtype probe: even uint16s of f32 storage are random mantissa halves.
__global__ void k_detect(const void* sf, int* flag)
{
    const unsigned short* u = (const unsigned short*)sf;
    int sane = 0;
    for (int i = 0; i < 64; i++){
        unsigned short v = u[2*i];
        int e = (v >> 7) & 0xFF;
        if (e == 0 || (e >= 100 && e <= 140)) sane++;
    }
    *flag = (sane >= 48) ? 1 : 0;
}

// ---- convert+transpose all weights into bf16 arena; biases (BN-folded) into f32 arena ----
__global__ __launch_bounds__(256) void k_convert(
    const void* qkvw, const void* outw, const void* fw1, const void* fw2,
    const void* gwl, const void* gwr,
    const void* W1, const void* b1, const void* g1, const void* be1, const void* m1, const void* v1,
    const void* W2, const void* b2, const void* g2, const void* be2, const void* m2, const void* v2,
    const void* W3, const void* b3, const void* g3, const void* be3, const void* m3, const void* v3,
    const void* qkvb, const void* outb, const void* fb1, const void* fb2,
    const void* gbl, const void* gbr,
    const int* flagp, bf16* WB, float* BB)
{
    const int f = *flagp;
    size_t idx = (size_t)blockIdx.x*256 + threadIdx.x;
    if (idx < WB_TOT){
        float v;
        if (idx < WB_OUT){            size_t i=idx-WB_QKV; int l=i/110592; int r=i%110592; int n=r/192, k=r%192;
            v = ldf(qkvw, (size_t)l*110592 + (size_t)k*576 + n, f);
        } else if (idx < WB_FW1){     size_t i=idx-WB_OUT; int l=i/36864; int r=i%36864; int n=r/192, k=r%192;
            v = ldf(outw, (size_t)l*36864 + (size_t)k*192 + n, f);
        } else if (idx < WB_FW2){     size_t i=idx-WB_FW1; int l=i/147456; int r=i%147456; int n=r/192, k=r%192;
            v = ldf(fw1, (size_t)l*147456 + (size_t)k*768 + n, f);
        } else if (idx < WB_GAT){     size_t i=idx-WB_FW2; int l=i/147456; int r=i%147456; int n=r/768, k=r%768;
            v = ldf(fw2, (size_t)l*147456 + (size_t)k*192 + n, f);
        } else if (idx < WB_W1){      size_t i=idx-WB_GAT; int l=i/442368; int r=i%442368; int n=r/192, k=r%192;
            if (n < 1152) v = ldf(gwl, (size_t)l*221184 + (size_t)k*1152 + n, f);
            else          v = ldf(gwr, (size_t)l*221184 + (size_t)k*1152 + (n-1152), f);
        } else if (idx < WB_W2){      size_t i=idx-WB_W1; int o=i%64;
            float s = ldf(g1,o,f)*rsqrtf(ldf(v1,o,f)+1e-5f);
            v = ldf(W1, i, f) * s;
        } else if (idx < WB_W3T){     size_t i=idx-WB_W2; int o=i%256;
            float s = ldf(g2,o,f)*rsqrtf(ldf(v2,o,f)+1e-5f);
            v = ldf(W2, i, f) * s;
        } else {                      size_t i=idx-WB_W3T; int n=i/256, k=i%256;
            float s = ldf(g3,n,f)*rsqrtf(ldf(v3,n,f)+1e-5f);
            v = ldf(W3, (size_t)k*192 + n, f) * s;
        }
        WB[idx] = __float2bfloat16(v);
    } else if (idx < WB_TOT + BB_TOT){
        size_t j = idx - WB_TOT;
        float v;
        if (j < BB_OUT)        v = ldf(qkvb, j, f);
        else if (j < BB_FW1)   v = ldf(outb, j-BB_OUT, f);
        else if (j < BB_FW2)   v = ldf(fb1, j-BB_FW1, f);
        else if (j < BB_GAT)   v = ldf(fb2, j-BB_FW2, f);
        else if (j < BB_B1){   size_t i=j-BB_GAT; int l=i/2304; int o=i%2304;
            v = (o<1152) ? ldf(gbl, (size_t)l*1152+o, f) : ldf(gbr, (size_t)l*1152+o-1152, f);
        } else if (j < BB_B2){ int o=j-BB_B1;
            float s = ldf(g1,o,f)*rsqrtf(ldf(v1,o,f)+1e-5f);
            v = (ldf(b1,o,f)-ldf(m1,o,f))*s + ldf(be1,o,f);
        } else if (j < BB_B3){ int o=j-BB_B2;
            float s = ldf(g2,o,f)*rsqrtf(ldf(v2,o,f)+1e-5f);
            v = (ldf(b2,o,f)-ldf(m2,o,f))*s + ldf(be2,o,f);
        } else {               int o=j-BB_B3;
            float s = ldf(g3,o,f)*rsqrtf(ldf(v3,o,f)+1e-5f);
            v = (ldf(b3,o,f)-ldf(m3,o,f))*s + ldf(be3,o,f);
        }
        BB[j] = v;
    }
}

// ---- MLP stages 1+2: in16 -> 64 -> 256 (relu, BN folded), 16 rows/block ----
__global__ __launch_bounds__(256) void k_mlp_a(
    const void* sf, const int* ids, const void* emb, const int* flagp,
    const bf16* __restrict__ WB, const float* __restrict__ BB, bf16* h2g)
{
    __shared__ float in16[16][16];
    __shared__ float h1[16][64];
    const int f = *flagp;
    int tid = threadIdx.x;
    int row0 = blockIdx.x * 16;
    {
        int r = tid >> 4, i = tid & 15;
        int row = row0 + r;
        float v;
        if (i < 4) v = ldf(sf, (size_t)row*4 + i, f);
        else {
            int id = ids[row / T_]; if (id < 0) id = 0; if (id > 599) id = 599;
            v = ldf(emb, (size_t)id*12 + (i-4), f);
        }
        in16[r][i] = v;
    }
    __syncthreads();
    {
        int o = tid & 63, rg = tid >> 6;
        float acc[4];
        float bv = BB[BB_B1 + o];
        #pragma unroll
        for (int j=0;j<4;j++) acc[j] = bv;
        for (int i=0;i<16;i++){
            float w = b2f(WB[WB_W1 + i*64 + o]);
            #pragma unroll
            for (int j=0;j<4;j++) acc[j] += in16[rg*4+j][i]*w;
        }
        #pragma unroll
        for (int j=0;j<4;j++) h1[rg*4+j][o] = acc[j] > 0.f ? acc[j] : 0.f;
    }
    __syncthreads();
    {
        int o = tid;
        float acc[16];
        float bv = BB[BB_B2 + o];
        #pragma unroll
        for (int r=0;r<16;r++) acc[r] = bv;
        for (int i=0;i<64;i++){
            float w = b2f(WB[WB_W2 + i*256 + o]);
            #pragma unroll
            for (int r=0;r<16;r++) acc[r] += h1[r][i]*w;
        }
        for (int r=0;r<16;r++){
            float v = acc[r] > 0.f ? acc[r] : 0.f;
            h2g[(size_t)(row0+r)*256 + o] = __float2bfloat16(v);
        }
    }
}

// ---- MFMA GEMM: C[rows x N] = A[rows x K](bf16) @ Wt[N x K]^T + bias ----
// mode 0: bf16 store | 1: GELU bf16 | 2: outf = res + v | 3: relu -> out0(flag dtype) & xf = relu + PE
__global__ __launch_bounds__(256) void k_mgemm(
    const bf16* __restrict__ A, const bf16* __restrict__ Wt, const float* __restrict__ bias,
    bf16* outh, float* outf, const float* __restrict__ res, void* out0, const int* flagp,
    int K, int N, int mode)
{
    __shared__ short As[64*200];
    __shared__ short Bs[64*200];
    int tid = threadIdx.x;
    int w = tid >> 6, lane = tid & 63, q = lane >> 4, li = lane & 15;
    int m0 = blockIdx.x * 64, n0 = blockIdx.y * 64;
    const int f = flagp ? *flagp : 0;
    f32x4 acc[4];
    #pragma unroll
    for (int nt=0;nt<4;nt++) acc[nt] = (f32x4){0.f,0.f,0.f,0.f};
    int nkc = (K + 191) / 192;
    for (int kc = 0; kc < nkc; kc++){
        int kcw = K - kc*192; if (kcw > 192) kcw = 192;
        int vr = kcw >> 3;
        const bf16* Ab = A  + (size_t)m0*K + kc*192;
        const bf16* Bb = Wt + (size_t)n0*K + kc*192;
        for (int idx = tid; idx < 64*vr; idx += 256){
            int r = idx / vr, kv = idx - r*vr;
            *(short8*)&As[r*200 + kv*8] = *(const short8*)&Ab[(size_t)r*K + kv*8];
        }
        for (int idx = tid; idx < 64*vr; idx += 256){
            int r = idx / vr, kv = idx - r*vr;
            *(short8*)&Bs[r*200 + kv*8] = *(const short8*)&Bb[(size_t)r*K + kv*8];
        }
        __syncthreads();
        int kkn = kcw >> 5;
        for (int kk = 0; kk < kkn; kk++){
            int ko = kk*32 + q*8;
            short8 a = *(short8*)&As[(w*16+li)*200 + ko];
            #pragma unroll
            for (int nt = 0; nt < 4; nt++){
                short8 b = *(short8*)&Bs[(nt*16+li)*200 + ko];
                acc[nt] = __builtin_amdgcn_mfma_f32_16x16x32_bf16(a, b, acc[nt], 0, 0, 0);
            }
        }
        __syncthreads();
    }
    int rb = m0 + w*16 + q*4;
    #pragma unroll
    for (int nt = 0; nt < 4; nt++){
        int col = n0 + nt*16 + li;
        float bv = bias[col];
        #pragma unroll
        for (int p = 0; p < 4; p++){
            int row = rb + p;
            float v = acc[nt][p] + bv;
            size_t idx = (size_t)row*N + col;
            if (mode == 0) outh[idx] = __float2bfloat16(v);
            else if (mode == 1) outh[idx] = __float2bfloat16(0.5f*v*(1.f + erff(v*0.70710678118654752f)));
            else if (mode == 2) outf[idx] = v + res[idx];
            else {
                float r2 = v > 0.f ? v : 0.f;
                if (f) ((bf16*)out0)[idx] = __float2bfloat16(r2);
                else   ((float*)out0)[idx] = r2;
                int t = row % T_;
                int i2 = col & ~1;
                float dv = expf((float)i2 * (-9.210340371976184f/192.f));
                float ang = (float)t * dv;
                outf[idx] = r2 + ((col & 1) ? cosf(ang) : sinf(ang));
            }
        }
    }
}

// ---- LayerNorm (one wave per row), optional permute to node order ----
__global__ __launch_bounds__(256) void k_ln(const float* __restrict__ x, const void* g, const void* b,
                     size_t gOff, const int* flagp, bf16* out, int permute)
{
    const int f = *flagp;
    int tid = threadIdx.x;
    int row = blockIdx.x*4 + (tid>>6);
    int lane = tid & 63;
    const float* xr = x + (size_t)row*192;
    float v0 = xr[lane], v1 = xr[lane+64], v2 = xr[lane+128];
    float s = v0+v1+v2;
    float qq = v0*v0+v1*v1+v2*v2;
    #pragma unroll
    for (int off=32; off; off>>=1){ s += __shfl_xor(s, off); qq += __shfl_xor(qq, off); }
    float mean = s * (1.f/192.f);
    float var  = qq * (1.f/192.f) - mean*mean;
    float rs = rsqrtf(var + 1e-5f);
    int orow = row;
    if (permute){ int n = row/T_, t = row%T_; int bb = n/A_, a = n%A_; orow = (bb*T_+t)*A_ + a; }
    bf16* op = out + (size_t)orow*192;
    op[lane]     = __float2bfloat16((v0-mean)*rs*ldf(g,gOff+lane,f)     + ldf(b,gOff+lane,f));
    op[lane+64]  = __float2bfloat16((v1-mean)*rs*ldf(g,gOff+lane+64,f)  + ldf(b,gOff+lane+64,f));
    op[lane+128] = __float2bfloat16((v2-mean)*rs*ldf(g,gOff+lane+128,f) + ldf(b,gOff+lane+128,f));
}

// ---- causal attention, one wave per (sequence, head) ----
__global__ __launch_bounds__(64) void k_attn(bfp qkv, bf16* attn_o)
{
    __shared__ float Ks[80][32];
    __shared__ float Vs[80][32];
    int bid = blockIdx.x; int n = bid / H_; int h = bid % H_;
    int tid = threadIdx.x;
    for (int idx=tid; idx<80*32; idx+=64){
        int t = idx>>5, c = idx&31;
        const bf16* rp = qkv + (size_t)(n*T_+t)*576;
        Ks[t][c] = b2f(rp[192 + h*32 + c]);
        Vs[t][c] = b2f(rp[384 + h*32 + c]);
    }
    __syncthreads();
    for (int q = tid; q < T_; q += 64){
        float qv[32];
        const bf16* rp = qkv + (size_t)(n*T_+q)*576 + h*32;
        #pragma unroll
        for (int c=0;c<32;c++) qv[c] = b2f(rp[c]);
        float m = -1e30f;
        for (int j=0;j<=q;j++){
            float sv=0.f;
            #pragma unroll
            for (int c=0;c<32;c++) sv += qv[c]*Ks[j][c];
            m = fmaxf(m, sv*0.17677669529663687f);
        }
        float den = 0.f;
        float acc[32];
        #pragma unroll
        for (int c=0;c<32;c++) acc[c]=0.f;
        for (int j=0;j<=q;j++){
            float sv=0.f;
            #pragma unroll
            for (int c=0;c<32;c++) sv += qv[c]*Ks[j][c];
            float e = expf(sv*0.17677669529663687f - m);
            den += e;
            #pragma unroll
            for (int c=0;c<32;c++) acc[c] += e*Vs[j][c];
        }
        float inv = 1.f/den;
        bf16* op = attn_o + (size_t)(n*T_+q)*192 + h*32;
        #pragma unroll
        for (int c=0;c<32;c++) op[c] = __float2bfloat16(acc[c]*inv);
    }
}

// ---- self-loop attr = mean of incoming edge attrs ----
__global__ __launch_bounds__(256) void k_loopea(const int* __restrict__ eidx, const void* ea, const int* flagp, float* lea)
{
    const int f = *flagp;
    int id = blockIdx.x*256 + threadIdx.x;
    if (id >= G_*A_) return;
    int g = id / A_, a = id % A_;
    float s0=0.f, s1=0.f; int cnt=0;
    for (int e=0;e<E_;e++){
        if (eidx[E_ + e] == a){
            s0 += ldf(ea, (size_t)(g*E_+e)*2,   f);
            s1 += ldf(ea, (size_t)(g*E_+e)*2+1, f);
            cnt++;
        }
    }
    if (cnt < 1) cnt = 1;
    lea[id*2]   = s0/(float)cnt;
    lea[id*2+1] = s1/(float)cnt;
}

// ---- GAT edge logits, one wave per edge (wide grid) ----
__global__ __launch_bounds__(256) void k_alpha(bfp xlr,
                        const float* __restrict__ lea, const int* __restrict__ eidx,
                        const void* ea, const void* gwe, size_t geOff,
                        const void* gatt, size_t gaOff, const int* flagp,
                        float* alpha, int g0)
{
    const int f = *flagp;
    int wid = blockIdx.x*4 + (threadIdx.x>>6);
    int lane = threadIdx.x & 63;
    if (wid >= GCH_*E2_) return;
    int gl = wid / E2_, el = wid % E2_;
    int gg = g0 + gl;
    int s, d; float f0, f1;
    if (el < E_){
        s = eidx[el]; d = eidx[E_+el];
        f0 = ldf(ea, (size_t)(gg*E_+el)*2, f); f1 = ldf(ea, (size_t)(gg*E_+el)*2+1, f);
    } else {
        s = d = el - E_;
        f0 = lea[(gg*A_+s)*2]; f1 = lea[(gg*A_+s)*2+1];
    }
    const bf16* xls = xlr + (size_t)(gl*A_+s)*2304;
    const bf16* xrd = xlr + (size_t)(gl*A_+d)*2304 + 1152;
    for (int h=0; h<H_; h++){
        float p = 0.f;
        #pragma unroll
        for (int c3=0;c3<3;c3++){
            int hc = h*192 + c3*64 + lane;
            float m = b2f(xls[hc]) + b2f(xrd[hc]) + f0*ldf(gwe,geOff+hc,f) + f1*ldf(gwe,geOff+1152+hc,f);
            m = m > 0.f ? m : 0.2f*m;
            p += m * ldf(gatt,gaOff+hc,f);
        }
        #pragma unroll
        for (int off=32; off; off>>=1) p += __shfl_xor(p, off);
        if (lane==0) alpha[(size_t)wid*H_ + h] = p;
    }
}

// ---- GAT segment softmax + aggregate, one block per dst node ----
__global__ __launch_bounds__(192) void k_segagg(bfp xlr, const float* __restrict__ alpha,
                         const int* __restrict__ eidx, const void* gbias, size_t gbOff,
                         const int* flagp, float* xf, int g0)
{
    __shared__ int e_src[12];
    __shared__ int e_el[12];
    __shared__ float al[12][6];
    __shared__ float w[12][6];
    __shared__ int cnt;
    const int f = *flagp;
    int node = blockIdx.x;
    int gl = node / A_, a = node % A_;
    int gg = g0 + gl;
    int tid = threadIdx.x;
    if (tid==0) cnt = 0;
    __syncthreads();
    if (tid < E_){
        if (eidx[E_+tid] == a){
            int pos = atomicAdd(&cnt, 1);
            if (pos < 12){ e_src[pos] = eidx[tid]; e_el[pos] = tid; }
        }
    } else if (tid == E_){
        int pos = atomicAdd(&cnt, 1);
        if (pos < 12){ e_src[pos] = a; e_el[pos] = E_ + a; }
    }
    __syncthreads();
    if (tid < 72){
        int e = tid / 6, h = tid % 6;
        al[e][h] = alpha[(size_t)(gl*E2_ + e_el[e])*H_ + h];
    }
    __syncthreads();
    if (tid < 6){
        float m = -1e30f;
        for (int e=0;e<12;e++) m = fmaxf(m, al[e][tid]);
        float den = 0.f;
        for (int e=0;e<12;e++){ float ex = expf(al[e][tid]-m); w[e][tid] = ex; den += ex; }
        float inv = 1.f/den;
        for (int e=0;e<12;e++) w[e][tid] *= inv;
    }
    __syncthreads();
    int c = tid;
    float acc = 0.f;
    for (int e=0;e<12;e++){
        const bf16* xp = xlr + (size_t)(gl*A_ + e_src[e])*2304 + c;
        #pragma unroll
        for (int h=0;h<6;h++) acc += w[e][h]*b2f(xp[h*192]);
    }
    int b = gg / T_, t = gg % T_;
    int xrow = (b*A_ + a)*T_ + t;
    xf[(size_t)xrow*192 + c] += acc*(1.f/6.f) + ldf(gbias, gbOff + c, f);
}

__global__ __launch_bounds__(256) void k_store(const float* __restrict__ xf, void* out, const int* flagp)
{
    const int f = *flagp;
    int i = blockIdx.x*256 + threadIdx.x;
    if (i < ROWS_*192){
        if (f) ((bf16*)out)[1474560 + i] = __float2bfloat16(xf[i]);
        else   ((float*)out)[1474560 + i] = xf[i];
    }
}

extern "C" void kernel_launch(void* const* d_in, const int* in_sizes, int n_in,
                              void* d_out, int out_size, void* d_ws, size_t ws_size,
                              hipStream_t stream)
{
    const void* sf   = d_in[0];
    const int* ids  = (const int*)d_in[2];
    const int* eidx = (const int*)d_in[3];
    const void* ea   = d_in[4];
    const void* emb  = d_in[5];
    const void *laW1=d_in[6],  *lab1=d_in[7];
    const void *bn1g=d_in[8],  *bn1b=d_in[9],  *bn1m=d_in[10], *bn1v=d_in[11];
    const void *laW2=d_in[12], *lab2=d_in[13];
    const void *bn2g=d_in[14], *bn2b=d_in[15], *bn2m=d_in[16], *bn2v=d_in[17];
    const void *laW3=d_in[18], *lab3=d_in[19];
    const void *bn3g=d_in[20], *bn3b=d_in[21], *bn3m=d_in[22], *bn3v=d_in[23];
    const void *ln1g=d_in[24], *ln1b=d_in[25];
    const void *qkvw=d_in[26], *qkvb=d_in[27];
    const void *outw=d_in[28], *outb=d_in[29];
    const void *ln2g=d_in[30], *ln2b=d_in[31];
    const void *fw1 =d_in[32], *fb1 =d_in[33];
    const void *fw2 =d_in[34], *fb2 =d_in[35];
    const void *gwl =d_in[36], *gbl =d_in[37];
    const void *gwr =d_in[38], *gbr =d_in[39];
    const void *gwe =d_in[40];
    const void *gatt=d_in[41];
    const void *gbias=d_in[42];
    const void *ng  =d_in[43], *nb  =d_in[44];

    float* ws = (float*)d_ws;
    float* xf  = ws;                          // [0, 1474560)
    bf16*  xn  = (bf16*)(ws + 1474560);       // 1,474,560 bf16
    bf16*  qkv = (bf16*)(ws + 2211840);       // 4,423,680 bf16
    bf16*  ao  = (bf16*)(ws + 4423680);       // 1,474,560 bf16
    bf16*  hb  = (bf16*)(ws + 2211840);       // overlays qkv+ao (FFN hidden)
    bf16*  h2  = (bf16*)(ws + 2211840);       // overlays (MLP hidden)
    bf16*  xlr = (bf16*)(ws + 2211840);       // overlays (GAT chunk lr, 4,423,680 bf16)
    float* lea = ws + 5160960;                // 15,360
    int*  flag = (int*)(ws + 5176320);
    bf16*  WB  = (bf16*)(ws + 5176328);       // 2,720,768 bf16
    float* BB  = ws + 6536712;                // 12,608 f32
    float* alp = ws + 6549320;                // 138,240 f32 (chunk edge logits)
    (void)ws_size; (void)in_sizes; (void)n_in; (void)out_size;

    k_detect<<<1, 1, 0, stream>>>(sf, flag);
    k_convert<<<(WB_TOT+BB_TOT+255)/256, 256, 0, stream>>>(
        qkvw, outw, fw1, fw2, gwl, gwr,
        laW1, lab1, bn1g, bn1b, bn1m, bn1v,
        laW2, lab2, bn2g, bn2b, bn2m, bn2v,
        laW3, lab3, bn3g, bn3b, bn3m, bn3v,
        qkvb, outb, fb1, fb2, gbl, gbr, flag, WB, BB);
    k_mlp_a<<<ROWS_/16, 256, 0, stream>>>(sf, ids, emb, flag, WB, BB, h2);
    k_mgemm<<<dim3(ROWS_/64, 3), 256, 0, stream>>>(h2, WB + WB_W3T, BB + BB_B3,
        nullptr, xf, nullptr, d_out, flag, 256, 192, 3);
    k_loopea<<<(G_*A_+255)/256, 256, 0, stream>>>(eidx, ea, flag, lea);

    for (int l=0; l<3; l++){
        k_ln<<<ROWS_/4, 256, 0, stream>>>(xf, ln1g, ln1b, (size_t)l*192, flag, xn, 0);
        k_mgemm<<<dim3(ROWS_/64, 9), 256, 0, stream>>>(xn, WB + WB_QKV + (size_t)l*110592,
            BB + BB_QKV + l*576, qkv, nullptr, nullptr, nullptr, nullptr, 192, 576, 0);
        k_attn<<<N_*H_, 64, 0, stream>>>(qkv, ao);
        k_mgemm<<<dim3(ROWS_/64, 3), 256, 0, stream>>>(ao, WB + WB_OUT + (size_t)l*36864,
            BB + BB_OUT + l*192, nullptr, xf, xf, nullptr, nullptr, 192, 192, 2);
        k_ln<<<ROWS_/4, 256, 0, stream>>>(xf, ln2g, ln2b, (size_t)l*192, flag, xn, 0);
        k_mgemm<<<dim3(ROWS_/64, 12), 256, 0, stream>>>(xn, WB + WB_FW1 + (size_t)l*147456,
            BB + BB_FW1 + l*768, hb, nullptr, nullptr, nullptr, nullptr, 192, 768, 1);
        k_mgemm<<<dim3(ROWS_/64, 3), 256, 0, stream>>>(hb, WB + WB_FW2 + (size_t)l*147456,
            BB + BB_FW2 + l*192, nullptr, xf, xf, nullptr, nullptr, 768, 192, 2);
        k_ln<<<ROWS_/4, 256, 0, stream>>>(xf, ng, nb, (size_t)l*192, flag, xn, 1);
        for (int c=0; c<NCHUNK_; c++){
            int g0 = c*GCH_;
            const bf16* xnc = xn + (size_t)g0*A_*192;
            k_mgemm<<<dim3(RCH_/64, 36), 256, 0, stream>>>(xnc, WB + WB_GAT + (size_t)l*442368,
                BB + BB_GAT + l*2304, xlr, nullptr, nullptr, nullptr, nullptr, 192, 2304, 0);
            k_alpha<<<GCH_*E2_/4, 256, 0, stream>>>(xlr, lea, eidx, ea,
                gwe, (size_t)l*2*1152, gatt, (size_t)l*1152, flag, alp, g0);
            k_segagg<<<GCH_*A_, 192, 0, stream>>>(xlr, alp, eidx, gbias, (size_t)l*192, flag, xf, g0);
        }
    }
    k_store<<<(ROWS_*192+255)/256, 256, 0, stream>>>(xf, d_out, flag);
}

// Round 7
// 1210.454 us; speedup vs baseline: 2.3019x; 1.1205x over previous
//
#include <hip/hip_runtime.h>
#include <hip/hip_bf16.h>
#include <math.h>

#define A_   12
#define H_   6
#define N_   96
#define T_   80
#define G_   640
#define E_   132
#define E2_  144
#define ROWS_ 7680
#define NCHUNK_ 4
#define GCH_ (G_/NCHUNK_)        /* 160 graphs per chunk */
#define RCH_ (GCH_*A_)           /* 1920 rows per chunk */

typedef const __hip_bfloat16* bfp;
typedef __hip_bfloat16 bf16;
typedef __attribute__((ext_vector_type(8))) short short8;
typedef __attribute__((ext_vector_type(4))) short short4v;
typedef __attribute__((ext_vector_type(4))) float f32x4;

// ---- bf16 weight arena element offsets (in bf16 units) ----
#define WB_QKV   0                /* [3][576][192]  */
#define WB_OUT   331776           /* [3][192][192]  */
#define WB_FW1   442368           /* [3][768][192]  */
#define WB_FW2   884736           /* [3][192][768]  */
#define WB_GAT   1327104          /* [3][2304][192] (gwl|gwr) */
#define WB_W1    2654208          /* [16][64] BN-folded */
#define WB_W2    2655232          /* [64][256] BN-folded */
#define WB_W3T   2671616          /* [192][256] BN-folded, transposed */
#define WB_GWE   2720768          /* [3][2304] */
#define WB_GATT  2727680          /* [3][1152] */
#define WB_TOT   2731136
// ---- f32 bias arena element offsets ----
#define BB_QKV   0                /* [3][576] */
#define BB_OUT   1728             /* [3][192] */
#define BB_FW1   2304             /* [3][768] */
#define BB_FW2   4608             /* [3][192] */
#define BB_GAT   5184             /* [3][2304] */
#define BB_B1    12096            /* [64]  folded */
#define BB_B2    12160            /* [256] folded */
#define BB_B3    12416            /* [192] folded */
#define BB_TOT   12608

__device__ __forceinline__ float b2f(bf16 x){ return __bfloat162float(x); }
__device__ __forceinline__ float ldf(const void* p, size_t i, int f){
    return f ? __bfloat162float(((const bf16*)p)[i]) : ((const float*)p)[i];
}

// dtype probe: even uint16s of f32 storage are random mantissa halves.
__global__ void k_detect(const void* sf, int* flag)
{
    const unsigned short* u = (const unsigned short*)sf;
    int sane = 0;
    for (int i = 0; i < 64; i++){
        unsigned short v = u[2*i];
        int e = (v >> 7) & 0xFF;
        if (e == 0 || (e >= 100 && e <= 140)) sane++;
    }
    *flag = (sane >= 48) ? 1 : 0;
}

// ---- convert+transpose all weights into bf16 arena; biases (BN-folded) into f32 arena ----
__global__ __launch_bounds__(256) void k_convert(
    const void* qkvw, const void* outw, const void* fw1, const void* fw2,
    const void* gwl, const void* gwr, const void* gwe, const void* gatt,
    const void* W1, const void* b1, const void* g1, const void* be1, const void* m1, const void* v1,
    const void* W2, const void* b2, const void* g2, const void* be2, const void* m2, const void* v2,
    const void* W3, const void* b3, const void* g3, const void* be3, const void* m3, const void* v3,
    const void* qkvb, const void* outb, const void* fb1, const void* fb2,
    const void* gbl, const void* gbr,
    const int* flagp, bf16* WB, float* BB)
{
    const int f = *flagp;
    size_t idx = (size_t)blockIdx.x*256 + threadIdx.x;
    if (idx < WB_TOT){
        float v;
        if (idx < WB_OUT){            size_t i=idx-WB_QKV; int l=i/110592; int r=i%110592; int n=r/192, k=r%192;
            v = ldf(qkvw, (size_t)l*110592 + (size_t)k*576 + n, f);
        } else if (idx < WB_FW1){     size_t i=idx-WB_OUT; int l=i/36864; int r=i%36864; int n=r/192, k=r%192;
            v = ldf(outw, (size_t)l*36864 + (size_t)k*192 + n, f);
        } else if (idx < WB_FW2){     size_t i=idx-WB_FW1; int l=i/147456; int r=i%147456; int n=r/192, k=r%192;
            v = ldf(fw1, (size_t)l*147456 + (size_t)k*768 + n, f);
        } else if (idx < WB_GAT){     size_t i=idx-WB_FW2; int l=i/147456; int r=i%147456; int n=r/768, k=r%768;
            v = ldf(fw2, (size_t)l*147456 + (size_t)k*192 + n, f);
        } else if (idx < WB_W1){      size_t i=idx-WB_GAT; int l=i/442368; int r=i%442368; int n=r/192, k=r%192;
            if (n < 1152) v = ldf(gwl, (size_t)l*221184 + (size_t)k*1152 + n, f);
            else          v = ldf(gwr, (size_t)l*221184 + (size_t)k*1152 + (n-1152), f);
        } else if (idx < WB_W2){      size_t i=idx-WB_W1; int o=i%64;
            float s = ldf(g1,o,f)*rsqrtf(ldf(v1,o,f)+1e-5f);
            v = ldf(W1, i, f) * s;
        } else if (idx < WB_W3T){     size_t i=idx-WB_W2; int o=i%256;
            float s = ldf(g2,o,f)*rsqrtf(ldf(v2,o,f)+1e-5f);
            v = ldf(W2, i, f) * s;
        } else if (idx < WB_GWE){     size_t i=idx-WB_W3T; int n=i/256, k=i%256;
            float s = ldf(g3,n,f)*rsqrtf(ldf(v3,n,f)+1e-5f);
            v = ldf(W3, (size_t)k*192 + n, f) * s;
        } else if (idx < WB_GATT){    size_t i=idx-WB_GWE;
            v = ldf(gwe, i, f);
        } else {                      size_t i=idx-WB_GATT;
            v = ldf(gatt, i, f);
        }
        WB[idx] = __float2bfloat16(v);
    } else if (idx < WB_TOT + BB_TOT){
        size_t j = idx - WB_TOT;
        float v;
        if (j < BB_OUT)        v = ldf(qkvb, j, f);
        else if (j < BB_FW1)   v = ldf(outb, j-BB_OUT, f);
        else if (j < BB_FW2)   v = ldf(fb1, j-BB_FW1, f);
        else if (j < BB_GAT)   v = ldf(fb2, j-BB_FW2, f);
        else if (j < BB_B1){   size_t i=j-BB_GAT; int l=i/2304; int o=i%2304;
            v = (o<1152) ? ldf(gbl, (size_t)l*1152+o, f) : ldf(gbr, (size_t)l*1152+o-1152, f);
        } else if (j < BB_B2){ int o=j-BB_B1;
            float s = ldf(g1,o,f)*rsqrtf(ldf(v1,o,f)+1e-5f);
            v = (ldf(b1,o,f)-ldf(m1,o,f))*s + ldf(be1,o,f);
        } else if (j < BB_B3){ int o=j-BB_B2;
            float s = ldf(g2,o,f)*rsqrtf(ldf(v2,o,f)+1e-5f);
            v = (ldf(b2,o,f)-ldf(m2,o,f))*s + ldf(be2,o,f);
        } else {               int o=j-BB_B3;
            float s = ldf(g3,o,f)*rsqrtf(ldf(v3,o,f)+1e-5f);
            v = (ldf(b3,o,f)-ldf(m3,o,f))*s + ldf(be3,o,f);
        }
        BB[j] = v;
    }
}

// ---- MLP stages 1+2: in16 -> 64 -> 256 (relu, BN folded), 16 rows/block ----
__global__ __launch_bounds__(256) void k_mlp_a(
    const void* sf, const int* ids, const void* emb, const int* flagp,
    const bf16* __restrict__ WB, const float* __restrict__ BB, bf16* h2g)
{
    __shared__ float in16[16][16];
    __shared__ float h1[16][64];
    const int f = *flagp;
    int tid = threadIdx.x;
    int row0 = blockIdx.x * 16;
    {
        int r = tid >> 4, i = tid & 15;
        int row = row0 + r;
        float v;
        if (i < 4) v = ldf(sf, (size_t)row*4 + i, f);
        else {
            int id = ids[row / T_]; if (id < 0) id = 0; if (id > 599) id = 599;
            v = ldf(emb, (size_t)id*12 + (i-4), f);
        }
        in16[r][i] = v;
    }
    __syncthreads();
    {
        int o = tid & 63, rg = tid >> 6;
        float acc[4];
        float bv = BB[BB_B1 + o];
        #pragma unroll
        for (int j=0;j<4;j++) acc[j] = bv;
        for (int i=0;i<16;i++){
            float w = b2f(WB[WB_W1 + i*64 + o]);
            #pragma unroll
            for (int j=0;j<4;j++) acc[j] += in16[rg*4+j][i]*w;
        }
        #pragma unroll
        for (int j=0;j<4;j++) h1[rg*4+j][o] = acc[j] > 0.f ? acc[j] : 0.f;
    }
    __syncthreads();
    {
        int o = tid;
        float acc[16];
        float bv = BB[BB_B2 + o];
        #pragma unroll
        for (int r=0;r<16;r++) acc[r] = bv;
        for (int i=0;i<64;i++){
            float w = b2f(WB[WB_W2 + i*256 + o]);
            #pragma unroll
            for (int r=0;r<16;r++) acc[r] += h1[r][i]*w;
        }
        for (int r=0;r<16;r++){
            float v = acc[r] > 0.f ? acc[r] : 0.f;
            h2g[(size_t)(row0+r)*256 + o] = __float2bfloat16(v);
        }
    }
}

// ---- MFMA GEMM: C[rows x N] = A[rows x K](bf16) @ Wt[N x K]^T + bias ----
// mode 0: bf16 store | 1: GELU bf16 | 2: outf = res + v | 3: relu -> out0(flag dtype) & xf = relu + PE
__global__ __launch_bounds__(256) void k_mgemm(
    const bf16* __restrict__ A, const bf16* __restrict__ Wt, const float* __restrict__ bias,
    bf16* outh, float* outf, const float* __restrict__ res, void* out0, const int* flagp,
    int K, int N, int mode)
{
    __shared__ short As[64*200];
    __shared__ short Bs[64*200];
    int tid = threadIdx.x;
    int w = tid >> 6, lane = tid & 63, q = lane >> 4, li = lane & 15;
    int m0 = blockIdx.x * 64, n0 = blockIdx.y * 64;
    const int f = flagp ? *flagp : 0;
    f32x4 acc[4];
    #pragma unroll
    for (int nt=0;nt<4;nt++) acc[nt] = (f32x4){0.f,0.f,0.f,0.f};
    int nkc = (K + 191) / 192;
    for (int kc = 0; kc < nkc; kc++){
        int kcw = K - kc*192; if (kcw > 192) kcw = 192;
        int vr = kcw >> 3;
        const bf16* Ab = A  + (size_t)m0*K + kc*192;
        const bf16* Bb = Wt + (size_t)n0*K + kc*192;
        for (int idx = tid; idx < 64*vr; idx += 256){
            int r = idx / vr, kv = idx - r*vr;
            *(short8*)&As[r*200 + kv*8] = *(const short8*)&Ab[(size_t)r*K + kv*8];
        }
        for (int idx = tid; idx < 64*vr; idx += 256){
            int r = idx / vr, kv = idx - r*vr;
            *(short8*)&Bs[r*200 + kv*8] = *(const short8*)&Bb[(size_t)r*K + kv*8];
        }
        __syncthreads();
        int kkn = kcw >> 5;
        for (int kk = 0; kk < kkn; kk++){
            int ko = kk*32 + q*8;
            short8 a = *(short8*)&As[(w*16+li)*200 + ko];
            #pragma unroll
            for (int nt = 0; nt < 4; nt++){
                short8 b = *(short8*)&Bs[(nt*16+li)*200 + ko];
                acc[nt] = __builtin_amdgcn_mfma_f32_16x16x32_bf16(a, b, acc[nt], 0, 0, 0);
            }
        }
        __syncthreads();
    }
    int rb = m0 + w*16 + q*4;
    #pragma unroll
    for (int nt = 0; nt < 4; nt++){
        int col = n0 + nt*16 + li;
        float bv = bias[col];
        #pragma unroll
        for (int p = 0; p < 4; p++){
            int row = rb + p;
            float v = acc[nt][p] + bv;
            size_t idx = (size_t)row*N + col;
            if (mode == 0) outh[idx] = __float2bfloat16(v);
            else if (mode == 1) outh[idx] = __float2bfloat16(0.5f*v*(1.f + erff(v*0.70710678118654752f)));
            else if (mode == 2) outf[idx] = v + res[idx];
            else {
                float r2 = v > 0.f ? v : 0.f;
                if (f) ((bf16*)out0)[idx] = __float2bfloat16(r2);
                else   ((float*)out0)[idx] = r2;
                int t = row % T_;
                int i2 = col & ~1;
                float dv = expf((float)i2 * (-9.210340371976184f/192.f));
                float ang = (float)t * dv;
                outf[idx] = r2 + ((col & 1) ? cosf(ang) : sinf(ang));
            }
        }
    }
}

// ---- LayerNorm (one wave per row), optional permute to node order ----
__global__ __launch_bounds__(256) void k_ln(const float* __restrict__ x, const void* g, const void* b,
                     size_t gOff, const int* flagp, bf16* out, int permute)
{
    const int f = *flagp;
    int tid = threadIdx.x;
    int row = blockIdx.x*4 + (tid>>6);
    int lane = tid & 63;
    const float* xr = x + (size_t)row*192;
    float v0 = xr[lane], v1 = xr[lane+64], v2 = xr[lane+128];
    float s = v0+v1+v2;
    float qq = v0*v0+v1*v1+v2*v2;
    #pragma unroll
    for (int off=32; off; off>>=1){ s += __shfl_xor(s, off); qq += __shfl_xor(qq, off); }
    float mean = s * (1.f/192.f);
    float var  = qq * (1.f/192.f) - mean*mean;
    float rs = rsqrtf(var + 1e-5f);
    int orow = row;
    if (permute){ int n = row/T_, t = row%T_; int bb = n/A_, a = n%A_; orow = (bb*T_+t)*A_ + a; }
    bf16* op = out + (size_t)orow*192;
    op[lane]     = __float2bfloat16((v0-mean)*rs*ldf(g,gOff+lane,f)     + ldf(b,gOff+lane,f));
    op[lane+64]  = __float2bfloat16((v1-mean)*rs*ldf(g,gOff+lane+64,f)  + ldf(b,gOff+lane+64,f));
    op[lane+128] = __float2bfloat16((v2-mean)*rs*ldf(g,gOff+lane+128,f) + ldf(b,gOff+lane+128,f));
}

// ---- causal attention, one wave per (seq, head, 16-query tile); online softmax ----
// lanes: qi = tid&15 (query in tile), p = tid>>4 (channel quarter: 8 ch each)
__global__ __launch_bounds__(64) void k_attn(bfp qkv, bf16* attn_o)
{
    __shared__ float Ks[80][32];
    __shared__ float Vs[80][32];
    int bid = blockIdx.x;
    int qt = bid % 5;
    int nh = bid / 5;
    int n = nh / H_, h = nh % H_;
    int tid = threadIdx.x;
    for (int idx = tid; idx < 640; idx += 64){
        int r = idx >> 3, c4 = (idx & 7) << 2;
        const bf16* rp = qkv + (size_t)(n*T_+r)*576 + h*32 + c4;
        short4v kv = *(const short4v*)(rp + 192);
        short4v vv = *(const short4v*)(rp + 384);
        f32x4 kf, vf;
        #pragma unroll
        for (int e=0;e<4;e++){
            kf[e] = __uint_as_float(((unsigned)(unsigned short)kv[e])<<16);
            vf[e] = __uint_as_float(((unsigned)(unsigned short)vv[e])<<16);
        }
        *(f32x4*)&Ks[r][c4] = kf;
        *(f32x4*)&Vs[r][c4] = vf;
    }
    __syncthreads();
    int qi = tid & 15, p = tid >> 4;
    int q = qt*16 + qi;
    float qv[8];
    const bf16* qp = qkv + (size_t)(n*T_+q)*576 + h*32 + p*8;
    #pragma unroll
    for (int c=0;c<8;c++) qv[c] = b2f(qp[c]);
    float m = -1e30f, l = 0.f;
    float acc[8];
    #pragma unroll
    for (int c=0;c<8;c++) acc[c]=0.f;
    int jmax = qt*16 + 15;
    for (int j = 0; j <= jmax; j++){
        float s = 0.f;
        #pragma unroll
        for (int c=0;c<8;c++) s += qv[c]*Ks[j][p*8+c];
        s += __shfl_xor(s, 16);
        s += __shfl_xor(s, 32);
        s *= 0.17677669529663687f;
        if (j > q) s = -1e30f;
        float mn = fmaxf(m, s);
        float corr = expf(m - mn);
        float e = expf(s - mn);
        l = l*corr + e;
        #pragma unroll
        for (int c=0;c<8;c++) acc[c] = acc[c]*corr + e*Vs[j][p*8+c];
        m = mn;
    }
    float inv = 1.f/l;
    bf16* op = attn_o + (size_t)(n*T_+q)*192 + h*32 + p*8;
    #pragma unroll
    for (int c=0;c<8;c++) op[c] = __float2bfloat16(acc[c]*inv);
}

// ---- self-loop attr = mean of incoming edge attrs ----
__global__ __launch_bounds__(256) void k_loopea(const int* __restrict__ eidx, const void* ea, const int* flagp, float* lea)
{
    const int f = *flagp;
    int id = blockIdx.x*256 + threadIdx.x;
    if (id >= G_*A_) return;
    int g = id / A_, a = id % A_;
    float s0=0.f, s1=0.f; int cnt=0;
    for (int e=0;e<E_;e++){
        if (eidx[E_ + e] == a){
            s0 += ldf(ea, (size_t)(g*E_+e)*2,   f);
            s1 += ldf(ea, (size_t)(g*E_+e)*2+1, f);
            cnt++;
        }
    }
    if (cnt < 1) cnt = 1;
    lea[id*2]   = s0/(float)cnt;
    lea[id*2+1] = s1/(float)cnt;
}

// ---- GAT edge logits, one wave per edge (wide grid); gwe/gatt from bf16 arena ----
__global__ __launch_bounds__(256) void k_alpha(bfp xlr,
                        const float* __restrict__ lea, const int* __restrict__ eidx,
                        const void* ea, const bf16* __restrict__ gweb,
                        const bf16* __restrict__ gattb, const int* flagp,
                        float* alpha, int g0)
{
    const int f = *flagp;
    int wid = blockIdx.x*4 + (threadIdx.x>>6);
    int lane = threadIdx.x & 63;
    if (wid >= GCH_*E2_) return;
    int gl = wid / E2_, el = wid % E2_;
    int gg = g0 + gl;
    int s, d; float f0, f1;
    if (el < E_){
        s = eidx[el]; d = eidx[E_+el];
        f0 = ldf(ea, (size_t)(gg*E_+el)*2, f); f1 = ldf(ea, (size_t)(gg*E_+el)*2+1, f);
    } else {
        s = d = el - E_;
        f0 = lea[(gg*A_+s)*2]; f1 = lea[(gg*A_+s)*2+1];
    }
    const bf16* xls = xlr + (size_t)(gl*A_+s)*2304;
    const bf16* xrd = xlr + (size_t)(gl*A_+d)*2304 + 1152;
    for (int h=0; h<H_; h++){
        float p = 0.f;
        #pragma unroll
        for (int c3=0;c3<3;c3++){
            int hc = h*192 + c3*64 + lane;
            float m = b2f(xls[hc]) + b2f(xrd[hc]) + f0*b2f(gweb[hc]) + f1*b2f(gweb[1152+hc]);
            m = m > 0.f ? m : 0.2f*m;
            p += m * b2f(gattb[hc]);
        }
        #pragma unroll
        for (int off=32; off; off>>=1) p += __shfl_xor(p, off);
        if (lane==0) alpha[(size_t)wid*H_ + h] = p;
    }
}

// ---- GAT segment softmax + aggregate, one block per dst node ----
__global__ __launch_bounds__(192) void k_segagg(bfp xlr, const float* __restrict__ alpha,
                         const int* __restrict__ eidx, const void* gbias, size_t gbOff,
                         const int* flagp, float* xf, int g0)
{
    __shared__ int e_src[12];
    __shared__ int e_el[12];
    __shared__ float al[12][6];
    __shared__ float w[12][6];
    __shared__ int cnt;
    const int f = *flagp;
    int node = blockIdx.x;
    int gl = node / A_, a = node % A_;
    int gg = g0 + gl;
    int tid = threadIdx.x;
    if (tid==0) cnt = 0;
    __syncthreads();
    if (tid < E_){
        if (eidx[E_+tid] == a){
            int pos = atomicAdd(&cnt, 1);
            if (pos < 12){ e_src[pos] = eidx[tid]; e_el[pos] = tid; }
        }
    } else if (tid == E_){
        int pos = atomicAdd(&cnt, 1);
        if (pos < 12){ e_src[pos] = a; e_el[pos] = E_ + a; }
    }
    __syncthreads();
    if (tid < 72){
        int e = tid / 6, h = tid % 6;
        al[e][h] = alpha[(size_t)(gl*E2_ + e_el[e])*H_ + h];
    }
    __syncthreads();
    if (tid < 6){
        float m = -1e30f;
        for (int e=0;e<12;e++) m = fmaxf(m, al[e][tid]);
        float den = 0.f;
        for (int e=0;e<12;e++){ float ex = expf(al[e][tid]-m); w[e][tid] = ex; den += ex; }
        float inv = 1.f/den;
        for (int e=0;e<12;e++) w[e][tid] *= inv;
    }
    __syncthreads();
    int c = tid;
    float acc = 0.f;
    for (int e=0;e<12;e++){
        const bf16* xp = xlr + (size_t)(gl*A_ + e_src[e])*2304 + c;
        #pragma unroll
        for (int h=0;h<6;h++) acc += w[e][h]*b2f(xp[h*192]);
    }
    int b = gg / T_, t = gg % T_;
    int xrow = (b*A_ + a)*T_ + t;
    xf[(size_t)xrow*192 + c] += acc*(1.f/6.f) + ldf(gbias, gbOff + c, f);
}

__global__ __launch_bounds__(256) void k_store(const float* __restrict__ xf, void* out, const int* flagp)
{
    const int f = *flagp;
    int i = blockIdx.x*256 + threadIdx.x;
    if (i < ROWS_*192){
        if (f) ((bf16*)out)[1474560 + i] = __float2bfloat16(xf[i]);
        else   ((float*)out)[1474560 + i] = xf[i];
    }
}

extern "C" void kernel_launch(void* const* d_in, const int* in_sizes, int n_in,
                              void* d_out, int out_size, void* d_ws, size_t ws_size,
                              hipStream_t stream)
{
    const void* sf   = d_in[0];
    const int* ids  = (const int*)d_in[2];
    const int* eidx = (const int*)d_in[3];
    const void* ea   = d_in[4];
    const void* emb  = d_in[5];
    const void *laW1=d_in[6],  *lab1=d_in[7];
    const void *bn1g=d_in[8],  *bn1b=d_in[9],  *bn1m=d_in[10], *bn1v=d_in[11];
    const void *laW2=d_in[12], *lab2=d_in[13];
    const void *bn2g=d_in[14], *bn2b=d_in[15], *bn2m=d_in[16], *bn2v=d_in[17];
    const void *laW3=d_in[18], *lab3=d_in[19];
    const void *bn3g=d_in[20], *bn3b=d_in[21], *bn3m=d_in[22], *bn3v=d_in[23];
    const void *ln1g=d_in[24], *ln1b=d_in[25];
    const void *qkvw=d_in[26], *qkvb=d_in[27];
    const void *outw=d_in[28], *outb=d_in[29];
    const void *ln2g=d_in[30], *ln2b=d_in[31];
    const void *fw1 =d_in[32], *fb1 =d_in[33];
    const void *fw2 =d_in[34], *fb2 =d_in[35];
    const void *gwl =d_in[36], *gbl =d_in[37];
    const void *gwr =d_in[38], *gbr =d_in[39];
    const void *gwe =d_in[40];
    const void *gatt=d_in[41];
    const void *gbias=d_in[42];
    const void *ng  =d_in[43], *nb  =d_in[44];

    float* ws = (float*)d_ws;
    float* xf  = ws;                          // [0, 1474560)
    bf16*  xn  = (bf16*)(ws + 1474560);       // 1,474,560 bf16
    bf16*  qkv = (bf16*)(ws + 2211840);       // 4,423,680 bf16
    bf16*  ao  = (bf16*)(ws + 4423680);       // 1,474,560 bf16
    bf16*  hb  = (bf16*)(ws + 2211840);       // overlays qkv+ao (FFN hidden)
    bf16*  h2  = (bf16*)(ws + 2211840);       // overlays (MLP hidden)
    bf16*  xlr = (bf16*)(ws + 2211840);       // overlays (GAT chunk lr, 4,423,680 bf16)
    float* lea = ws + 5160960;                // 15,360
    int*  flag = (int*)(ws + 5176320);
    bf16*  WB  = (bf16*)(ws + 5176328);       // 2,731,136 bf16 -> 1,365,568 f32
    float* BB  = ws + 6541896;                // 12,608 f32
    float* alp = ws + 6554504;                // 138,240 f32 (chunk edge logits)
    (void)ws_size; (void)in_sizes; (void)n_in; (void)out_size;

    k_detect<<<1, 1, 0, stream>>>(sf, flag);
    k_convert<<<(WB_TOT+BB_TOT+255)/256, 256, 0, stream>>>(
        qkvw, outw, fw1, fw2, gwl, gwr, gwe, gatt,
        laW1, lab1, bn1g, bn1b, bn1m, bn1v,
        laW2, lab2, bn2g, bn2b, bn2m, bn2v,
        laW3, lab3, bn3g, bn3b, bn3m, bn3v,
        qkvb, outb, fb1, fb2, gbl, gbr, flag, WB, BB);
    k_mlp_a<<<ROWS_/16, 256, 0, stream>>>(sf, ids, emb, flag, WB, BB, h2);
    k_mgemm<<<dim3(ROWS_/64, 3), 256, 0, stream>>>(h2, WB + WB_W3T, BB + BB_B3,
        nullptr, xf, nullptr, d_out, flag, 256, 192, 3);
    k_loopea<<<(G_*A_+255)/256, 256, 0, stream>>>(eidx, ea, flag, lea);

    for (int l=0; l<3; l++){
        k_ln<<<ROWS_/4, 256, 0, stream>>>(xf, ln1g, ln1b, (size_t)l*192, flag, xn, 0);
        k_mgemm<<<dim3(ROWS_/64, 9), 256, 0, stream>>>(xn, WB + WB_QKV + (size_t)l*110592,
            BB + BB_QKV + l*576, qkv, nullptr, nullptr, nullptr, nullptr, 192, 576, 0);
        k_attn<<<N_*H_*5, 64, 0, stream>>>(qkv, ao);
        k_mgemm<<<dim3(ROWS_/64, 3), 256, 0, stream>>>(ao, WB + WB_OUT + (size_t)l*36864,
            BB + BB_OUT + l*192, nullptr, xf, xf, nullptr, nullptr, 192, 192, 2);
        k_ln<<<ROWS_/4, 256, 0, stream>>>(xf, ln2g, ln2b, (size_t)l*192, flag, xn, 0);
        k_mgemm<<<dim3(ROWS_/64, 12), 256, 0, stream>>>(xn, WB + WB_FW1 + (size_t)l*147456,
            BB + BB_FW1 + l*768, hb, nullptr, nullptr, nullptr, nullptr, 192, 768, 1);
        k_mgemm<<<dim3(ROWS_/64, 3), 256, 0, stream>>>(hb, WB + WB_FW2 + (size_t)l*147456,
            BB + BB_FW2 + l*192, nullptr, xf, xf, nullptr, nullptr, 768, 192, 2);
        k_ln<<<ROWS_/4, 256, 0, stream>>>(xf, ng, nb, (size_t)l*192, flag, xn, 1);
        for (int c=0; c<NCHUNK_; c++){
            int g0 = c*GCH_;
            const bf16* xnc = xn + (size_t)g0*A_*192;
            k_mgemm<<<dim3(RCH_/64, 36), 256, 0, stream>>>(xnc, WB + WB_GAT + (size_t)l*442368,
                BB + BB_GAT + l*2304, xlr, nullptr, nullptr, nullptr, nullptr, 192, 2304, 0);
            k_alpha<<<GCH_*E2_/4, 256, 0, stream>>>(xlr, lea, eidx, ea,
                WB + WB_GWE + (size_t)l*2304, WB + WB_GATT + (size_t)l*1152, flag, alp, g0);
            k_segagg<<<GCH_*A_, 192, 0, stream>>>(xlr, alp, eidx, gbias, (size_t)l*192, flag, xf, g0);
        }
    }
    k_store<<<(ROWS_*192+255)/256, 256, 0, stream>>>(xf, d_out, flag);
}

// Round 8
// 1015.827 us; speedup vs baseline: 2.7429x; 1.1916x over previous
//
#include <hip/hip_runtime.h>
#include <hip/hip_bf16.h>
#include <math.h>

#define A_   12
#define H_   6
#define N_   96
#define T_   80
#define G_   640
#define E_   132
#define E2_  144
#define ROWS_ 7680

typedef const __hip_bfloat16* bfp;
typedef __hip_bfloat16 bf16;
typedef __attribute__((ext_vector_type(8))) short short8;
typedef __attribute__((ext_vector_type(4))) short short4v;
typedef __attribute__((ext_vector_type(4))) float f32x4;

// ---- bf16 weight arena element offsets (in bf16 units) ----
#define WB_QKV   0                /* [3][576][192]  */
#define WB_OUT   331776           /* [3][192][192]  */
#define WB_FW1   442368           /* [3][768][192]  */
#define WB_FW2   884736           /* [3][192][768]  */
#define WB_GAT   1327104          /* [3][2304][192] (gwl|gwr) */
#define WB_W1    2654208          /* [16][64] BN-folded */
#define WB_W2    2655232          /* [64][256] BN-folded */
#define WB_W3T   2671616          /* [192][256] BN-folded, transposed */
#define WB_GWE   2720768          /* [3][2304] */
#define WB_GATT  2727680          /* [3][1152] */
#define WB_TOT   2731136
// ---- f32 bias arena element offsets ----
#define BB_QKV   0                /* [3][576] */
#define BB_OUT   1728             /* [3][192] */
#define BB_FW1   2304             /* [3][768] */
#define BB_FW2   4608             /* [3][192] */
#define BB_GAT   5184             /* [3][2304] */
#define BB_B1    12096            /* [64]  folded */
#define BB_B2    12160            /* [256] folded */
#define BB_B3    12416            /* [192] folded */
#define BB_TOT   12608

__device__ __forceinline__ float b2f(bf16 x){ return __bfloat162float(x); }
__device__ __forceinline__ float ldf(const void* p, size_t i, int f){
    return f ? __bfloat162float(((const bf16*)p)[i]) : ((const float*)p)[i];
}

// dtype probe: even uint16s of f32 storage are random mantissa halves.
__global__ void k_detect(const void* sf, int* flag)
{
    const unsigned short* u = (const unsigned short*)sf;
    int sane = 0;
    for (int i = 0; i < 64; i++){
        unsigned short v = u[2*i];
        int e = (v >> 7) & 0xFF;
        if (e == 0 || (e >= 100 && e <= 140)) sane++;
    }
    *flag = (sane >= 48) ? 1 : 0;
}

// ---- convert+transpose all weights into bf16 arena; biases (BN-folded) into f32 arena ----
__global__ __launch_bounds__(256) void k_convert(
    const void* qkvw, const void* outw, const void* fw1, const void* fw2,
    const void* gwl, const void* gwr, const void* gwe, const void* gatt,
    const void* W1, const void* b1, const void* g1, const void* be1, const void* m1, const void* v1,
    const void* W2, const void* b2, const void* g2, const void* be2, const void* m2, const void* v2,
    const void* W3, const void* b3, const void* g3, const void* be3, const void* m3, const void* v3,
    const void* qkvb, const void* outb, const void* fb1, const void* fb2,
    const void* gbl, const void* gbr,
    const int* flagp, bf16* WB, float* BB)
{
    const int f = *flagp;
    size_t idx = (size_t)blockIdx.x*256 + threadIdx.x;
    if (idx < WB_TOT){
        float v;
        if (idx < WB_OUT){            size_t i=idx-WB_QKV; int l=i/110592; int r=i%110592; int n=r/192, k=r%192;
            v = ldf(qkvw, (size_t)l*110592 + (size_t)k*576 + n, f);
        } else if (idx < WB_FW1){     size_t i=idx-WB_OUT; int l=i/36864; int r=i%36864; int n=r/192, k=r%192;
            v = ldf(outw, (size_t)l*36864 + (size_t)k*192 + n, f);
        } else if (idx < WB_FW2){     size_t i=idx-WB_FW1; int l=i/147456; int r=i%147456; int n=r/192, k=r%192;
            v = ldf(fw1, (size_t)l*147456 + (size_t)k*768 + n, f);
        } else if (idx < WB_GAT){     size_t i=idx-WB_FW2; int l=i/147456; int r=i%147456; int n=r/768, k=r%768;
            v = ldf(fw2, (size_t)l*147456 + (size_t)k*192 + n, f);
        } else if (idx < WB_W1){      size_t i=idx-WB_GAT; int l=i/442368; int r=i%442368; int n=r/192, k=r%192;
            if (n < 1152) v = ldf(gwl, (size_t)l*221184 + (size_t)k*1152 + n, f);
            else          v = ldf(gwr, (size_t)l*221184 + (size_t)k*1152 + (n-1152), f);
        } else if (idx < WB_W2){      size_t i=idx-WB_W1; int o=i%64;
            float s = ldf(g1,o,f)*rsqrtf(ldf(v1,o,f)+1e-5f);
            v = ldf(W1, i, f) * s;
        } else if (idx < WB_W3T){     size_t i=idx-WB_W2; int o=i%256;
            float s = ldf(g2,o,f)*rsqrtf(ldf(v2,o,f)+1e-5f);
            v = ldf(W2, i, f) * s;
        } else if (idx < WB_GWE){     size_t i=idx-WB_W3T; int n=i/256, k=i%256;
            float s = ldf(g3,n,f)*rsqrtf(ldf(v3,n,f)+1e-5f);
            v = ldf(W3, (size_t)k*192 + n, f) * s;
        } else if (idx < WB_GATT){    size_t i=idx-WB_GWE;
            v = ldf(gwe, i, f);
        } else {                      size_t i=idx-WB_GATT;
            v = ldf(gatt, i, f);
        }
        WB[idx] = __float2bfloat16(v);
    } else if (idx < WB_TOT + BB_TOT){
        size_t j = idx - WB_TOT;
        float v;
        if (j < BB_OUT)        v = ldf(qkvb, j, f);
        else if (j < BB_FW1)   v = ldf(outb, j-BB_OUT, f);
        else if (j < BB_FW2)   v = ldf(fb1, j-BB_FW1, f);
        else if (j < BB_GAT)   v = ldf(fb2, j-BB_FW2, f);
        else if (j < BB_B1){   size_t i=j-BB_GAT; int l=i/2304; int o=i%2304;
            v = (o<1152) ? ldf(gbl, (size_t)l*1152+o, f) : ldf(gbr, (size_t)l*1152+o-1152, f);
        } else if (j < BB_B2){ int o=j-BB_B1;
            float s = ldf(g1,o,f)*rsqrtf(ldf(v1,o,f)+1e-5f);
            v = (ldf(b1,o,f)-ldf(m1,o,f))*s + ldf(be1,o,f);
        } else if (j < BB_B3){ int o=j-BB_B2;
            float s = ldf(g2,o,f)*rsqrtf(ldf(v2,o,f)+1e-5f);
            v = (ldf(b2,o,f)-ldf(m2,o,f))*s + ldf(be2,o,f);
        } else {               int o=j-BB_B3;
            float s = ldf(g3,o,f)*rsqrtf(ldf(v3,o,f)+1e-5f);
            v = (ldf(b3,o,f)-ldf(m3,o,f))*s + ldf(be3,o,f);
        }
        BB[j] = v;
    }
}

// ---- MLP stages 1+2: in16 -> 64 -> 256 (relu, BN folded), 16 rows/block ----
__global__ __launch_bounds__(256) void k_mlp_a(
    const void* sf, const int* ids, const void* emb, const int* flagp,
    const bf16* __restrict__ WB, const float* __restrict__ BB, bf16* h2g)
{
    __shared__ float in16[16][16];
    __shared__ float h1[16][64];
    const int f = *flagp;
    int tid = threadIdx.x;
    int row0 = blockIdx.x * 16;
    {
        int r = tid >> 4, i = tid & 15;
        int row = row0 + r;
        float v;
        if (i < 4) v = ldf(sf, (size_t)row*4 + i, f);
        else {
            int id = ids[row / T_]; if (id < 0) id = 0; if (id > 599) id = 599;
            v = ldf(emb, (size_t)id*12 + (i-4), f);
        }
        in16[r][i] = v;
    }
    __syncthreads();
    {
        int o = tid & 63, rg = tid >> 6;
        float acc[4];
        float bv = BB[BB_B1 + o];
        #pragma unroll
        for (int j=0;j<4;j++) acc[j] = bv;
        for (int i=0;i<16;i++){
            float w = b2f(WB[WB_W1 + i*64 + o]);
            #pragma unroll
            for (int j=0;j<4;j++) acc[j] += in16[rg*4+j][i]*w;
        }
        #pragma unroll
        for (int j=0;j<4;j++) h1[rg*4+j][o] = acc[j] > 0.f ? acc[j] : 0.f;
    }
    __syncthreads();
    {
        int o = tid;
        float acc[16];
        float bv = BB[BB_B2 + o];
        #pragma unroll
        for (int r=0;r<16;r++) acc[r] = bv;
        for (int i=0;i<64;i++){
            float w = b2f(WB[WB_W2 + i*256 + o]);
            #pragma unroll
            for (int r=0;r<16;r++) acc[r] += h1[r][i]*w;
        }
        for (int r=0;r<16;r++){
            float v = acc[r] > 0.f ? acc[r] : 0.f;
            h2g[(size_t)(row0+r)*256 + o] = __float2bfloat16(v);
        }
    }
}

// ---- MFMA GEMM: C[rows x N] = A[rows x K](bf16) @ Wt[N x K]^T + bias ----
// mode 0: bf16 store | 1: GELU bf16 | 2: outf = res + v | 3: relu -> out0(flag dtype) & xf = relu + PE
__global__ __launch_bounds__(256) void k_mgemm(
    const bf16* __restrict__ A, const bf16* __restrict__ Wt, const float* __restrict__ bias,
    bf16* outh, float* outf, const float* __restrict__ res, void* out0, const int* flagp,
    int K, int N, int mode)
{
    __shared__ short As[64*200];
    __shared__ short Bs[64*200];
    int tid = threadIdx.x;
    int w = tid >> 6, lane = tid & 63, q = lane >> 4, li = lane & 15;
    int m0 = blockIdx.x * 64, n0 = blockIdx.y * 64;
    const int f = flagp ? *flagp : 0;
    f32x4 acc[4];
    #pragma unroll
    for (int nt=0;nt<4;nt++) acc[nt] = (f32x4){0.f,0.f,0.f,0.f};
    int nkc = (K + 191) / 192;
    for (int kc = 0; kc < nkc; kc++){
        int kcw = K - kc*192; if (kcw > 192) kcw = 192;
        int vr = kcw >> 3;
        const bf16* Ab = A  + (size_t)m0*K + kc*192;
        const bf16* Bb = Wt + (size_t)n0*K + kc*192;
        for (int idx = tid; idx < 64*vr; idx += 256){
            int r = idx / vr, kv = idx - r*vr;
            *(short8*)&As[r*200 + kv*8] = *(const short8*)&Ab[(size_t)r*K + kv*8];
        }
        for (int idx = tid; idx < 64*vr; idx += 256){
            int r = idx / vr, kv = idx - r*vr;
            *(short8*)&Bs[r*200 + kv*8] = *(const short8*)&Bb[(size_t)r*K + kv*8];
        }
        __syncthreads();
        int kkn = kcw >> 5;
        for (int kk = 0; kk < kkn; kk++){
            int ko = kk*32 + q*8;
            short8 a = *(short8*)&As[(w*16+li)*200 + ko];
            #pragma unroll
            for (int nt = 0; nt < 4; nt++){
                short8 b = *(short8*)&Bs[(nt*16+li)*200 + ko];
                acc[nt] = __builtin_amdgcn_mfma_f32_16x16x32_bf16(a, b, acc[nt], 0, 0, 0);
            }
        }
        __syncthreads();
    }
    int rb = m0 + w*16 + q*4;
    #pragma unroll
    for (int nt = 0; nt < 4; nt++){
        int col = n0 + nt*16 + li;
        float bv = bias[col];
        #pragma unroll
        for (int p = 0; p < 4; p++){
            int row = rb + p;
            float v = acc[nt][p] + bv;
            size_t idx = (size_t)row*N + col;
            if (mode == 0) outh[idx] = __float2bfloat16(v);
            else if (mode == 1) outh[idx] = __float2bfloat16(0.5f*v*(1.f + erff(v*0.70710678118654752f)));
            else if (mode == 2) outf[idx] = v + res[idx];
            else {
                float r2 = v > 0.f ? v : 0.f;
                if (f) ((bf16*)out0)[idx] = __float2bfloat16(r2);
                else   ((float*)out0)[idx] = r2;
                int t = row % T_;
                int i2 = col & ~1;
                float dv = expf((float)i2 * (-9.210340371976184f/192.f));
                float ang = (float)t * dv;
                outf[idx] = r2 + ((col & 1) ? cosf(ang) : sinf(ang));
            }
        }
    }
}

// ---- LayerNorm (one wave per row), optional permute to node order ----
__global__ __launch_bounds__(256) void k_ln(const float* __restrict__ x, const void* g, const void* b,
                     size_t gOff, const int* flagp, bf16* out, int permute)
{
    const int f = *flagp;
    int tid = threadIdx.x;
    int row = blockIdx.x*4 + (tid>>6);
    int lane = tid & 63;
    const float* xr = x + (size_t)row*192;
    float v0 = xr[lane], v1 = xr[lane+64], v2 = xr[lane+128];
    float s = v0+v1+v2;
    float qq = v0*v0+v1*v1+v2*v2;
    #pragma unroll
    for (int off=32; off; off>>=1){ s += __shfl_xor(s, off); qq += __shfl_xor(qq, off); }
    float mean = s * (1.f/192.f);
    float var  = qq * (1.f/192.f) - mean*mean;
    float rs = rsqrtf(var + 1e-5f);
    int orow = row;
    if (permute){ int n = row/T_, t = row%T_; int bb = n/A_, a = n%A_; orow = (bb*T_+t)*A_ + a; }
    bf16* op = out + (size_t)orow*192;
    op[lane]     = __float2bfloat16((v0-mean)*rs*ldf(g,gOff+lane,f)     + ldf(b,gOff+lane,f));
    op[lane+64]  = __float2bfloat16((v1-mean)*rs*ldf(g,gOff+lane+64,f)  + ldf(b,gOff+lane+64,f));
    op[lane+128] = __float2bfloat16((v2-mean)*rs*ldf(g,gOff+lane+128,f) + ldf(b,gOff+lane+128,f));
}

// ---- causal attention, one wave per (seq, head, 16-query tile); online softmax ----
__global__ __launch_bounds__(64) void k_attn(bfp qkv, bf16* attn_o)
{
    __shared__ float Ks[80][32];
    __shared__ float Vs[80][32];
    int bid = blockIdx.x;
    int qt = bid % 5;
    int nh = bid / 5;
    int n = nh / H_, h = nh % H_;
    int tid = threadIdx.x;
    for (int idx = tid; idx < 640; idx += 64){
        int r = idx >> 3, c4 = (idx & 7) << 2;
        const bf16* rp = qkv + (size_t)(n*T_+r)*576 + h*32 + c4;
        short4v kv = *(const short4v*)(rp + 192);
        short4v vv = *(const short4v*)(rp + 384);
        f32x4 kf, vf;
        #pragma unroll
        for (int e=0;e<4;e++){
            kf[e] = __uint_as_float(((unsigned)(unsigned short)kv[e])<<16);
            vf[e] = __uint_as_float(((unsigned)(unsigned short)vv[e])<<16);
        }
        *(f32x4*)&Ks[r][c4] = kf;
        *(f32x4*)&Vs[r][c4] = vf;
    }
    __syncthreads();
    int qi = tid & 15, p = tid >> 4;
    int q = qt*16 + qi;
    float qv[8];
    const bf16* qp = qkv + (size_t)(n*T_+q)*576 + h*32 + p*8;
    #pragma unroll
    for (int c=0;c<8;c++) qv[c] = b2f(qp[c]);
    float m = -1e30f, l = 0.f;
    float acc[8];
    #pragma unroll
    for (int c=0;c<8;c++) acc[c]=0.f;
    int jmax = qt*16 + 15;
    for (int j = 0; j <= jmax; j++){
        float s = 0.f;
        #pragma unroll
        for (int c=0;c<8;c++) s += qv[c]*Ks[j][p*8+c];
        s += __shfl_xor(s, 16);
        s += __shfl_xor(s, 32);
        s *= 0.17677669529663687f;
        if (j > q) s = -1e30f;
        float mn = fmaxf(m, s);
        float corr = expf(m - mn);
        float e = expf(s - mn);
        l = l*corr + e;
        #pragma unroll
        for (int c=0;c<8;c++) acc[c] = acc[c]*corr + e*Vs[j][p*8+c];
        m = mn;
    }
    float inv = 1.f/l;
    bf16* op = attn_o + (size_t)(n*T_+q)*192 + h*32 + p*8;
    #pragma unroll
    for (int c=0;c<8;c++) op[c] = __float2bfloat16(acc[c]*inv);
}

// ---- self-loop attr = mean of incoming edge attrs; one block per graph ----
__global__ __launch_bounds__(192) void k_loopea(const int* __restrict__ eidx, const void* ea,
                                                const int* flagp, float* lea)
{
    __shared__ float s0[A_], s1[A_];
    __shared__ int cnt[A_];
    const int f = *flagp;
    int g = blockIdx.x;
    int tid = threadIdx.x;
    if (tid < A_){ s0[tid] = 0.f; s1[tid] = 0.f; cnt[tid] = 0; }
    __syncthreads();
    if (tid < E_){
        int d = eidx[E_ + tid];
        float a0 = ldf(ea, (size_t)(g*E_+tid)*2,   f);
        float a1 = ldf(ea, (size_t)(g*E_+tid)*2+1, f);
        atomicAdd(&s0[d], a0);
        atomicAdd(&s1[d], a1);
        atomicAdd(&cnt[d], 1);
    }
    __syncthreads();
    if (tid < A_){
        int c = cnt[tid] < 1 ? 1 : cnt[tid];
        lea[(g*A_+tid)*2]   = s0[tid]/(float)c;
        lea[(g*A_+tid)*2+1] = s1[tid]/(float)c;
    }
}

// ---- GAT edge logits, one wave per edge (full graph) ----
__global__ __launch_bounds__(256) void k_alpha(bfp xlr,
                        const float* __restrict__ lea, const int* __restrict__ eidx,
                        const void* ea, const bf16* __restrict__ gweb,
                        const bf16* __restrict__ gattb, const int* flagp,
                        float* alpha)
{
    const int f = *flagp;
    int wid = blockIdx.x*4 + (threadIdx.x>>6);
    int lane = threadIdx.x & 63;
    if (wid >= G_*E2_) return;
    int gl = wid / E2_, el = wid % E2_;
    int s, d; float f0, f1;
    if (el < E_){
        s = eidx[el]; d = eidx[E_+el];
        f0 = ldf(ea, (size_t)(gl*E_+el)*2, f); f1 = ldf(ea, (size_t)(gl*E_+el)*2+1, f);
    } else {
        s = d = el - E_;
        f0 = lea[(gl*A_+s)*2]; f1 = lea[(gl*A_+s)*2+1];
    }
    const bf16* xls = xlr + (size_t)(gl*A_+s)*2304;
    const bf16* xrd = xlr + (size_t)(gl*A_+d)*2304 + 1152;
    for (int h=0; h<H_; h++){
        float p = 0.f;
        #pragma unroll
        for (int c3=0;c3<3;c3++){
            int hc = h*192 + c3*64 + lane;
            float m = b2f(xls[hc]) + b2f(xrd[hc]) + f0*b2f(gweb[hc]) + f1*b2f(gweb[1152+hc]);
            m = m > 0.f ? m : 0.2f*m;
            p += m * b2f(gattb[hc]);
        }
        #pragma unroll
        for (int off=32; off; off>>=1) p += __shfl_xor(p, off);
        if (lane==0) alpha[(size_t)wid*H_ + h] = p;
    }
}

// ---- GAT segment softmax + aggregate, one block per dst node (full graph) ----
__global__ __launch_bounds__(192) void k_segagg(bfp xlr, const float* __restrict__ alpha,
                         const int* __restrict__ eidx, const void* gbias, size_t gbOff,
                         const int* flagp, float* xf)
{
    __shared__ int e_src[12];
    __shared__ int e_el[12];
    __shared__ float al[12][6];
    __shared__ float w[12][6];
    __shared__ int cnt;
    const int f = *flagp;
    int node = blockIdx.x;
    int gl = node / A_, a = node % A_;
    int tid = threadIdx.x;
    if (tid==0) cnt = 0;
    __syncthreads();
    if (tid < E_){
        if (eidx[E_+tid] == a){
            int pos = atomicAdd(&cnt, 1);
            if (pos < 12){ e_src[pos] = eidx[tid]; e_el[pos] = tid; }
        }
    } else if (tid == E_){
        int pos = atomicAdd(&cnt, 1);
        if (pos < 12){ e_src[pos] = a; e_el[pos] = E_ + a; }
    }
    __syncthreads();
    if (tid < 72){
        int e = tid / 6, h = tid % 6;
        al[e][h] = alpha[(size_t)(gl*E2_ + e_el[e])*H_ + h];
    }
    __syncthreads();
    if (tid < 6){
        float m = -1e30f;
        for (int e=0;e<12;e++) m = fmaxf(m, al[e][tid]);
        float den = 0.f;
        for (int e=0;e<12;e++){ float ex = expf(al[e][tid]-m); w[e][tid] = ex; den += ex; }
        float inv = 1.f/den;
        for (int e=0;e<12;e++) w[e][tid] *= inv;
    }
    __syncthreads();
    int c = tid;
    float acc = 0.f;
    for (int e=0;e<12;e++){
        const bf16* xp = xlr + (size_t)(gl*A_ + e_src[e])*2304 + c;
        #pragma unroll
        for (int h=0;h<6;h++) acc += w[e][h]*b2f(xp[h*192]);
    }
    int b = gl / T_, t = gl % T_;
    int xrow = (b*A_ + a)*T_ + t;
    xf[(size_t)xrow*192 + c] += acc*(1.f/6.f) + ldf(gbias, gbOff + c, f);
}

__global__ __launch_bounds__(256) void k_store(const float* __restrict__ xf, void* out, const int* flagp)
{
    const int f = *flagp;
    int i = blockIdx.x*256 + threadIdx.x;
    if (i < ROWS_*192){
        if (f) ((bf16*)out)[1474560 + i] = __float2bfloat16(xf[i]);
        else   ((float*)out)[1474560 + i] = xf[i];
    }
}

extern "C" void kernel_launch(void* const* d_in, const int* in_sizes, int n_in,
                              void* d_out, int out_size, void* d_ws, size_t ws_size,
                              hipStream_t stream)
{
    const void* sf   = d_in[0];
    const int* ids  = (const int*)d_in[2];
    const int* eidx = (const int*)d_in[3];
    const void* ea   = d_in[4];
    const void* emb  = d_in[5];
    const void *laW1=d_in[6],  *lab1=d_in[7];
    const void *bn1g=d_in[8],  *bn1b=d_in[9],  *bn1m=d_in[10], *bn1v=d_in[11];
    const void *laW2=d_in[12], *lab2=d_in[13];
    const void *bn2g=d_in[14], *bn2b=d_in[15], *bn2m=d_in[16], *bn2v=d_in[17];
    const void *laW3=d_in[18], *lab3=d_in[19];
    const void *bn3g=d_in[20], *bn3b=d_in[21], *bn3m=d_in[22], *bn3v=d_in[23];
    const void *ln1g=d_in[24], *ln1b=d_in[25];
    const void *qkvw=d_in[26], *qkvb=d_in[27];
    const void *outw=d_in[28], *outb=d_in[29];
    const void *ln2g=d_in[30], *ln2b=d_in[31];
    const void *fw1 =d_in[32], *fb1 =d_in[33];
    const void *fw2 =d_in[34], *fb2 =d_in[35];
    const void *gwl =d_in[36], *gbl =d_in[37];
    const void *gwr =d_in[38], *gbr =d_in[39];
    const void *gwe =d_in[40];
    const void *gatt=d_in[41];
    const void *gbias=d_in[42];
    const void *ng  =d_in[43], *nb  =d_in[44];

    float* ws = (float*)d_ws;
    // layout (f32 units); peak ~13.0 M f32 = 52 MB (ws is ~268 MB per harness fill size)
    float* xf  = ws;                          // [0, 1474560)
    bf16*  xn  = (bf16*)(ws + 1474560);       // 1,474,560 bf16
    bf16*  qkv = (bf16*)(ws + 2211840);       // 4,423,680 bf16
    bf16*  ao  = (bf16*)(ws + 4423680);       // 1,474,560 bf16
    bf16*  hb  = (bf16*)(ws + 2211840);       // overlays qkv+ao (FFN hidden)
    bf16*  h2  = (bf16*)(ws + 2211840);       // overlays (MLP hidden)
    bf16*  xlr = (bf16*)(ws + 2211840);       // overlays (GAT full lr: 17,694,720 bf16)
    float* lea = ws + 11059200;               // 15,360
    int*  flag = (int*)(ws + 11074560);
    bf16*  WB  = (bf16*)(ws + 11074568);      // 2,731,136 bf16
    float* BB  = ws + 12440136;               // 12,608 f32
    float* alp = ws + 12452744;               // 552,960 f32 (full edge logits)
    (void)ws_size; (void)in_sizes; (void)n_in; (void)out_size;

    k_detect<<<1, 1, 0, stream>>>(sf, flag);
    k_convert<<<(WB_TOT+BB_TOT+255)/256, 256, 0, stream>>>(
        qkvw, outw, fw1, fw2, gwl, gwr, gwe, gatt,
        laW1, lab1, bn1g, bn1b, bn1m, bn1v,
        laW2, lab2, bn2g, bn2b, bn2m, bn2v,
        laW3, lab3, bn3g, bn3b, bn3m, bn3v,
        qkvb, outb, fb1, fb2, gbl, gbr, flag, WB, BB);
    k_mlp_a<<<ROWS_/16, 256, 0, stream>>>(sf, ids, emb, flag, WB, BB, h2);
    k_mgemm<<<dim3(ROWS_/64, 3), 256, 0, stream>>>(h2, WB + WB_W3T, BB + BB_B3,
        nullptr, xf, nullptr, d_out, flag, 256, 192, 3);
    k_loopea<<<G_, 192, 0, stream>>>(eidx, ea, flag, lea);

    for (int l=0; l<3; l++){
        k_ln<<<ROWS_/4, 256, 0, stream>>>(xf, ln1g, ln1b, (size_t)l*192, flag, xn, 0);
        k_mgemm<<<dim3(ROWS_/64, 9), 256, 0, stream>>>(xn, WB + WB_QKV + (size_t)l*110592,
            BB + BB_QKV + l*576, qkv, nullptr, nullptr, nullptr, nullptr, 192, 576, 0);
        k_attn<<<N_*H_*5, 64, 0, stream>>>(qkv, ao);
        k_mgemm<<<dim3(ROWS_/64, 3), 256, 0, stream>>>(ao, WB + WB_OUT + (size_t)l*36864,
            BB + BB_OUT + l*192, nullptr, xf, xf, nullptr, nullptr, 192, 192, 2);
        k_ln<<<ROWS_/4, 256, 0, stream>>>(xf, ln2g, ln2b, (size_t)l*192, flag, xn, 0);
        k_mgemm<<<dim3(ROWS_/64, 12), 256, 0, stream>>>(xn, WB + WB_FW1 + (size_t)l*147456,
            BB + BB_FW1 + l*768, hb, nullptr, nullptr, nullptr, nullptr, 192, 768, 1);
        k_mgemm<<<dim3(ROWS_/64, 3), 256, 0, stream>>>(hb, WB + WB_FW2 + (size_t)l*147456,
            BB + BB_FW2 + l*192, nullptr, xf, xf, nullptr, nullptr, 768, 192, 2);
        k_ln<<<ROWS_/4, 256, 0, stream>>>(xf, ng, nb, (size_t)l*192, flag, xn, 1);
        k_mgemm<<<dim3(ROWS_/64, 36), 256, 0, stream>>>(xn, WB + WB_GAT + (size_t)l*442368,
            BB + BB_GAT + l*2304, xlr, nullptr, nullptr, nullptr, nullptr, 192, 2304, 0);
        k_alpha<<<G_*E2_/4, 256, 0, stream>>>(xlr, lea, eidx, ea,
            WB + WB_GWE + (size_t)l*2304, WB + WB_GATT + (size_t)l*1152, flag, alp);
        k_segagg<<<G_*A_, 192, 0, stream>>>(xlr, alp, eidx, gbias, (size_t)l*192, flag, xf);
    }
    k_store<<<(ROWS_*192+255)/256, 256, 0, stream>>>(xf, d_out, flag);
}